// Round 1
// baseline (2381.163 us; speedup 1.0000x reference)
//
#include <hip/hip_runtime.h>
#include <math.h>

#define N_NODES 20000
#define N_EDGES 200000
#define XROW    1480   // EMB + MD

// ---------------- reduction helpers ----------------
__device__ __forceinline__ float wsum(float v){
#pragma unroll
  for (int o=32;o>0;o>>=1) v += __shfl_down(v,o);
  return v;
}
__device__ __forceinline__ float wmax(float v){
#pragma unroll
  for (int o=32;o>0;o>>=1) v = fmaxf(v,__shfl_down(v,o));
  return v;
}
// block=256 (4 waves)
__device__ __forceinline__ float bsum256(float v, float* red){
  int t=threadIdx.x;
  v = wsum(v);
  __syncthreads();
  if ((t&63)==0) red[t>>6]=v;
  __syncthreads();
  return red[0]+red[1]+red[2]+red[3];
}
__device__ __forceinline__ float bmax256(float v, float* red){
  int t=threadIdx.x;
  v = wmax(v);
  __syncthreads();
  if ((t&63)==0) red[t>>6]=v;
  __syncthreads();
  return fmaxf(fmaxf(red[0],red[1]),fmaxf(red[2],red[3]));
}

// ---------------- edge preprocessing (once, reused 3 layers) ----------------
__global__ void edge_count_kernel(const int* __restrict__ ei, const float* __restrict__ ea,
                                  int* __restrict__ cnt, float* __restrict__ easum, int E){
  int e = blockIdx.x*256 + threadIdx.x;
  if (e >= E) return;
  int dst = ei[E + e];
  atomicAdd(&cnt[dst], 1);
  atomicAdd(&easum[dst], ea[e]);
}

__launch_bounds__(1024)
__global__ void scan_kernel(const int* __restrict__ cnt, const float* __restrict__ easum,
                            int* __restrict__ off, float* __restrict__ loop_attr, int n){
  __shared__ int buf[1024];
  __shared__ int carry_s;
  if (threadIdx.x==0) carry_s = 0;
  __syncthreads();
  for (int base=0; base<n; base+=1024){
    int i = base + threadIdx.x;
    int v = (i<n)? cnt[i] : 0;
    if (i<n){
      loop_attr[i] = (v>0) ? easum[i]/(float)v : 0.f;  // fill='mean'
    }
    buf[threadIdx.x] = v;
    __syncthreads();
    for (int d2=1; d2<1024; d2<<=1){
      int tv = (threadIdx.x>=d2)? buf[threadIdx.x-d2] : 0;
      __syncthreads();
      buf[threadIdx.x] += tv;
      __syncthreads();
    }
    if (i<n) off[i] = carry_s + buf[threadIdx.x] - v;   // exclusive
    int tot = buf[1023];
    __syncthreads();
    if (threadIdx.x==0) carry_s += tot;
    __syncthreads();
  }
  if (threadIdx.x==0) off[n] = carry_s;
}

__global__ void edge_fill_kernel(const int* __restrict__ ei, const float* __restrict__ ea,
                                 const int* __restrict__ off, int* __restrict__ fill,
                                 int* __restrict__ csr_src, float* __restrict__ csr_ea, int E){
  int e = blockIdx.x*256 + threadIdx.x;
  if (e >= E) return;
  int dst = ei[E + e];
  int pos = off[dst] + atomicAdd(&fill[dst], 1);
  csr_src[pos] = ei[e];
  csr_ea[pos]  = ea[e];
}

// ---------------- cross-attention (rank-1 collapsed) ----------------
// K[j] = md @ ca_kw + kb ; V[j] = md @ ca_vw + vb   (md = x[0,1280:1480])
__global__ void kv_kernel(const float* __restrict__ x,
                          const float* __restrict__ kw, const float* __restrict__ kb,
                          const float* __restrict__ vw, const float* __restrict__ vb,
                          float* __restrict__ Kv, float* __restrict__ Vv){
  int j = threadIdx.x; // 256
  float ka = kb[j], va = vb[j];
  for (int k=0;k<200;k++){
    float m = x[1280+k];
    ka = fmaf(m, kw[k*256+j], ka);
    va = fmaf(m, vw[k*256+j], va);
  }
  Kv[j]=ka; Vv[j]=va;
}

// qK[i] = ca_qw[i,:] @ K  (i<1280) ;  Vo[j] = V @ ca_ow[:,j]  (j<1280)
__global__ void qkvo_kernel(const float* __restrict__ qw, const float* __restrict__ ow,
                            const float* __restrict__ Kv, const float* __restrict__ Vv,
                            float* __restrict__ qK, float* __restrict__ Vo){
  int idx = blockIdx.x*256 + threadIdx.x;
  if (idx < 1280){
    float a=0;
    for (int j=0;j<256;j++) a = fmaf(qw[idx*256+j], Kv[j], a);
    qK[idx]=a;
  } else if (idx < 2560){
    int j = idx-1280;
    float a=0;
    for (int i=0;i<256;i++) a = fmaf(Vv[i], ow[(size_t)i*1280+j], a);
    Vo[j]=a;
  }
}

// obW[j] = ca_ob @ g0_w[:,j] ; VoW[j] = Vo @ g0_w[:,j]   (j<1024)
__global__ void obw_kernel(const float* __restrict__ ob, const float* __restrict__ Vo,
                           const float* __restrict__ W, float* __restrict__ obW, float* __restrict__ VoW){
  int j = blockIdx.x*256 + threadIdx.x; // < 1024
  float a=0,b=0;
  for (int i=0;i<1280;i++){
    float w = W[(size_t)i*1024+j];
    a = fmaf(ob[i], w, a);
    b = fmaf(Vo[i], w, b);
  }
  obW[j]=a; VoW[j]=b;
}

// scores[n] = dot(xe[n], qK)   (scale 1/16 applied in softmax; qb·K const cancels)
__launch_bounds__(256)
__global__ void scores_kernel(const float* __restrict__ x, const float* __restrict__ qK,
                              float* __restrict__ scores, int n){
  __shared__ float qs[1280];
  int t = threadIdx.x;
  for (int i=t;i<1280;i+=256) qs[i]=qK[i];
  __syncthreads();
  int wid = t>>6, lane = t&63;
  int node = blockIdx.x*4 + wid;
  if (node >= n) return;
  const float4* row = (const float4*)(x + (size_t)node*XROW);
  float acc = 0;
#pragma unroll
  for (int it=0; it<5; it++){
    float4 v = row[lane + 64*it];
    float4 q = *(const float4*)&qs[4*(lane+64*it)];
    acc += v.x*q.x + v.y*q.y + v.z*q.z + v.w*q.w;
  }
  acc = wsum(acc);
  if (lane==0) scores[node] = acc;
}

__launch_bounds__(1024)
__global__ void softmax_nodes(const float* __restrict__ scores, float* __restrict__ wts, int n){
  __shared__ float red[16];
  int t = threadIdx.x, lane=t&63, wid=t>>6;
  float m = -INFINITY;
  for (int i=t;i<n;i+=1024) m = fmaxf(m, scores[i]);
  m = wmax(m);
  if (lane==0) red[wid]=m;
  __syncthreads();
  if (t==0){ float r=red[0]; for (int k=1;k<16;k++) r=fmaxf(r,red[k]); red[0]=r; }
  __syncthreads();
  float M = red[0];
  __syncthreads();
  float z=0;
  for (int i=t;i<n;i+=1024) z += expf((scores[i]-M)*(1.f/16.f));
  z = wsum(z);
  if (lane==0) red[wid]=z;
  __syncthreads();
  if (t==0){ float r=0; for (int k=0;k<16;k++) r+=red[k]; red[0]=r; }
  __syncthreads();
  float invZ = 1.f/red[0];
  for (int i=t;i<n;i+=1024) wts[i] = expf((scores[i]-M)*(1.f/16.f))*invZ;
}

// ---------------- f32 SGEMM: C[M,Nn] = A[M,K] @ B[K,Nn] (+ rank-1 epilogue) ----------------
// 128x128 tile, BK=8, 256 threads, 8x8 per thread.
__launch_bounds__(256)
__global__ void sgemm128(const float* __restrict__ A, int lda,
                         const float* __restrict__ B, int ldb,
                         float* __restrict__ C, int ldc,
                         int M, int K,
                         const float* __restrict__ addCol,   // obW (per col) or null
                         const float* __restrict__ vCol,     // VoW (per col)
                         const float* __restrict__ wRow)     // wts (per row)
{
  __shared__ float As[8][128];
  __shared__ float Bs[8][128];
  const int t  = threadIdx.x;
  const int bm = blockIdx.x*128;
  const int bn = blockIdx.y*128;
  const int arow = t>>1,  acol = (t&1)*4;
  const int brow = t>>5,  bcol = (t&31)*4;
  const int ty = t>>4, tx = t&15;
  float acc[8][8];
#pragma unroll
  for (int i=0;i<8;i++)
#pragma unroll
    for (int j=0;j<8;j++) acc[i][j]=0.f;

  const int gm_a = bm + arow;
  for (int k0=0;k0<K;k0+=8){
    float4 av = make_float4(0.f,0.f,0.f,0.f);
    if (gm_a < M) av = *(const float4*)(A + (size_t)gm_a*lda + k0 + acol);
    As[acol+0][arow]=av.x; As[acol+1][arow]=av.y; As[acol+2][arow]=av.z; As[acol+3][arow]=av.w;
    float4 bv = *(const float4*)(B + (size_t)(k0+brow)*ldb + bn + bcol);
    *(float4*)(&Bs[brow][bcol]) = bv;
    __syncthreads();
#pragma unroll
    for (int kk=0;kk<8;kk++){
      float a[8], b[8];
      *(float4*)(&a[0]) = *(const float4*)(&As[kk][ty*8]);
      *(float4*)(&a[4]) = *(const float4*)(&As[kk][ty*8+4]);
      *(float4*)(&b[0]) = *(const float4*)(&Bs[kk][tx*8]);
      *(float4*)(&b[4]) = *(const float4*)(&Bs[kk][tx*8+4]);
#pragma unroll
      for (int i=0;i<8;i++)
#pragma unroll
        for (int j=0;j<8;j++) acc[i][j] = fmaf(a[i], b[j], acc[i][j]);
    }
    __syncthreads();
  }
#pragma unroll
  for (int i=0;i<8;i++){
    int gm = bm + ty*8 + i;
    if (gm >= M) continue;
    float rs = wRow ? wRow[gm] : 0.f;
#pragma unroll
    for (int j=0;j<8;j+=4){
      int gn = bn + tx*8 + j;
      float4 v = make_float4(acc[i][j],acc[i][j+1],acc[i][j+2],acc[i][j+3]);
      if (addCol){
        v.x += addCol[gn+0] + rs*vCol[gn+0];
        v.y += addCol[gn+1] + rs*vCol[gn+1];
        v.z += addCol[gn+2] + rs*vCol[gn+2];
        v.w += addCol[gn+3] + rs*vCol[gn+3];
      }
      *(float4*)(C + (size_t)gm*ldc + gn) = v;
    }
  }
}

// ---------------- attention logits per node/head ----------------
// als[n,h] = h[n,h,:]·a_src[h], ald[n,h] = h[n,h,:]·a_dst[h]
template<int H>
__launch_bounds__(256)
__global__ void alsd_kernel(const float* __restrict__ h,
                            const float* __restrict__ a_src, const float* __restrict__ a_dst,
                            float* __restrict__ als, float* __restrict__ ald, int n){
  int gw = (blockIdx.x*256 + threadIdx.x) >> 6;
  int lane = threadIdx.x & 63;
  if (gw >= n*H) return;
  int node = gw / H, hd = gw % H;
  const float4* row = (const float4*)(h + (size_t)node*(256*H) + hd*256);
  const float4* as  = (const float4*)(a_src + hd*256);
  const float4* ad  = (const float4*)(a_dst + hd*256);
  float4 r = row[lane], a = as[lane], b = ad[lane];
  float s = r.x*a.x + r.y*a.y + r.z*a.z + r.w*a.w;
  float d = r.x*b.x + r.y*b.y + r.z*b.z + r.w*b.w;
  s = wsum(s); d = wsum(d);
  if (lane==0){ als[(size_t)node*H+hd]=s; ald[(size_t)node*H+hd]=d; }
}

// we[h] = sum_c We[h*256+c]*a_edge[h*256+c]
template<int H>
__global__ void we_kernel(const float* __restrict__ We, const float* __restrict__ a_edge,
                          float* __restrict__ we){
  int wid = threadIdx.x>>6, lane = threadIdx.x&63;
  if (wid < H){
    const float4* w4 = (const float4*)(We + wid*256);
    const float4* a4 = (const float4*)(a_edge + wid*256);
    float4 a = w4[lane], b = a4[lane];
    float v = a.x*b.x + a.y*b.y + a.z*b.z + a.w*b.w;
    v = wsum(v);
    if (lane==0) we[wid]=v;
  }
}

// ---------------- fused alpha-softmax + aggregate + bias + LN + ReLU ----------------
// one block per dst node; CSR edges + implicit self-loop (slot deg)
template<int H>
__launch_bounds__(256)
__global__ void gat_agg_ln(const float* __restrict__ h,
                           const float* __restrict__ als, const float* __restrict__ ald,
                           const int* __restrict__ off, const int* __restrict__ csr_src,
                           const float* __restrict__ csr_ea, const float* __restrict__ loop_attr,
                           const float* __restrict__ we,
                           const float* __restrict__ bias,
                           const float* __restrict__ ln_g, const float* __restrict__ ln_b,
                           float* __restrict__ out)
{
  constexpr int OUT = 256*H;
  const int i = blockIdx.x;
  const int t = threadIdx.x;
  __shared__ float red[4];
  __shared__ float w_lds[64*H];
  __shared__ int   src_lds[64];

  const int begin = off[i];
  const int deg   = off[i+1]-begin;
  const int S     = deg + 1;           // + self-loop

  float aldi[H], wei[H];
#pragma unroll
  for (int hh=0;hh<H;hh++){ aldi[hh]=ald[(size_t)i*H+hh]; wei[hh]=we[hh]; }
  const float lea = loop_attr[i];

  // pass 1: per-head max of leaky_relu(alpha)
  float tm[H];
#pragma unroll
  for (int hh=0;hh<H;hh++) tm[hh] = -INFINITY;
  for (int s=t; s<S; s+=256){
    int src  = (s<deg)? csr_src[begin+s] : i;
    float ev = (s<deg)? csr_ea[begin+s]  : lea;
#pragma unroll
    for (int hh=0;hh<H;hh++){
      float a = als[(size_t)src*H+hh] + aldi[hh] + ev*wei[hh];
      a = a>0.f ? a : 0.2f*a;
      tm[hh] = fmaxf(tm[hh], a);
    }
  }
  float M[H];
#pragma unroll
  for (int hh=0;hh<H;hh++) M[hh] = bmax256(tm[hh], red);

  // pass 2: sum of exp
  float ts[H];
#pragma unroll
  for (int hh=0;hh<H;hh++) ts[hh]=0.f;
  for (int s=t; s<S; s+=256){
    int src  = (s<deg)? csr_src[begin+s] : i;
    float ev = (s<deg)? csr_ea[begin+s]  : lea;
#pragma unroll
    for (int hh=0;hh<H;hh++){
      float a = als[(size_t)src*H+hh] + aldi[hh] + ev*wei[hh];
      a = a>0.f ? a : 0.2f*a;
      ts[hh] += expf(a - M[hh]);
    }
  }
  float invS[H];
#pragma unroll
  for (int hh=0;hh<H;hh++){
    float ssum = bsum256(ts[hh], red);
    invS[hh] = 1.f/(ssum + 1e-16f);
  }

  // pass 3: weighted aggregation; thread owns channels c0 = t*H .. t*H+H-1 (head = t*H>>8)
  const int ht = (t*H)>>8;
  float acc[H];
#pragma unroll
  for (int p=0;p<H;p++) acc[p]=0.f;

  for (int cb=0; cb<S; cb+=64){
    int m = min(64, S-cb);
    __syncthreads();
    if (t < m){
      int s = cb + t;
      int src  = (s<deg)? csr_src[begin+s] : i;
      float ev = (s<deg)? csr_ea[begin+s]  : lea;
      src_lds[t] = src;
#pragma unroll
      for (int hh=0;hh<H;hh++){
        float a = als[(size_t)src*H+hh] + aldi[hh] + ev*wei[hh];
        a = a>0.f ? a : 0.2f*a;
        w_lds[t*H+hh] = expf(a - M[hh]) * invS[hh];
      }
    }
    __syncthreads();
    for (int j=0;j<m;j++){
      const float* row = h + (size_t)src_lds[j]*OUT;
      float w = w_lds[j*H + ht];
      if constexpr (H==4){
        float4 r = *(const float4*)(row + 4*t);
        acc[0] = fmaf(w, r.x, acc[0]);
        acc[1] = fmaf(w, r.y, acc[1]);
        acc[2] = fmaf(w, r.z, acc[2]);
        acc[3] = fmaf(w, r.w, acc[3]);
      } else {
        acc[0] = fmaf(w, row[t], acc[0]);
      }
    }
  }

  // bias + LayerNorm + ReLU
  const int c0 = t*H;
  float vals[H];
  if constexpr (H==4){
    float4 b4 = *(const float4*)(bias + c0);
    vals[0]=acc[0]+b4.x; vals[1]=acc[1]+b4.y; vals[2]=acc[2]+b4.z; vals[3]=acc[3]+b4.w;
  } else {
    vals[0] = acc[0] + bias[c0];
  }
  float ls=0;
#pragma unroll
  for (int p=0;p<H;p++) ls += vals[p];
  float mu = bsum256(ls, red) * (1.f/OUT);
  float lv=0;
#pragma unroll
  for (int p=0;p<H;p++){ float d=vals[p]-mu; lv += d*d; }
  float var = bsum256(lv, red) * (1.f/OUT);
  float inv = rsqrtf(var + 1e-5f);

  if constexpr (H==4){
    float4 g4 = *(const float4*)(ln_g + c0);
    float4 b4 = *(const float4*)(ln_b + c0);
    float4 o;
    o.x = fmaxf((vals[0]-mu)*inv*g4.x + b4.x, 0.f);
    o.y = fmaxf((vals[1]-mu)*inv*g4.y + b4.y, 0.f);
    o.z = fmaxf((vals[2]-mu)*inv*g4.z + b4.z, 0.f);
    o.w = fmaxf((vals[3]-mu)*inv*g4.w + b4.w, 0.f);
    *(float4*)(out + (size_t)i*OUT + c0) = o;
  } else {
    float y = (vals[0]-mu)*inv*ln_g[c0] + ln_b[c0];
    out[(size_t)i*OUT + c0] = fmaxf(y, 0.f);
  }
}

// ---------------- mean pool + classifier ----------------
__global__ void colsum_kernel(const float* __restrict__ h2, float* __restrict__ gsum, int n){
  int c = threadIdx.x; // 256
  float acc=0;
  for (int i=blockIdx.x;i<n;i+=gridDim.x) acc += h2[(size_t)i*256 + c];
  atomicAdd(&gsum[c], acc);
}

__launch_bounds__(128)
__global__ void cls_kernel(const float* __restrict__ gsum,
                           const float* __restrict__ w1, const float* __restrict__ b1,
                           const float* __restrict__ w2, const float* __restrict__ b2,
                           float* __restrict__ outp){
  __shared__ float g[256];
  __shared__ float hid[128];
  int t = threadIdx.x;
  g[t]     = gsum[t]    *(1.f/N_NODES);
  g[t+128] = gsum[t+128]*(1.f/N_NODES);
  __syncthreads();
  float a = b1[t];
  for (int c=0;c<256;c++) a = fmaf(g[c], w1[c*128+t], a);
  hid[t] = fmaxf(a, 0.f);
  __syncthreads();
  if (t<2){
    float o = b2[t];
    for (int j=0;j<128;j++) o = fmaf(hid[j], w2[j*2+t], o);
    outp[t] = o;
  }
}

// ---------------- launch ----------------
extern "C" void kernel_launch(void* const* d_in, const int* in_sizes, int n_in,
                              void* d_out, int out_size, void* d_ws, size_t ws_size,
                              hipStream_t stream)
{
  const float* x      = (const float*)d_in[0];
  const int*   ei     = (const int*)  d_in[1];
  const float* ea     = (const float*)d_in[2];
  const float* ca_qw  = (const float*)d_in[3];
  // d_in[4] = ca_qb: constant shift in softmax, cancels — unused
  const float* ca_kw  = (const float*)d_in[5];
  const float* ca_kb  = (const float*)d_in[6];
  const float* ca_vw  = (const float*)d_in[7];
  const float* ca_vb  = (const float*)d_in[8];
  const float* ca_ow  = (const float*)d_in[9];
  const float* ca_ob  = (const float*)d_in[10];
  const float* g0_w   = (const float*)d_in[11];
  const float* g0_ew  = (const float*)d_in[12];
  const float* g0_as  = (const float*)d_in[13];
  const float* g0_ad  = (const float*)d_in[14];
  const float* g0_ae  = (const float*)d_in[15];
  const float* g0_b   = (const float*)d_in[16];
  const float* ln0_g  = (const float*)d_in[17];
  const float* ln0_b  = (const float*)d_in[18];
  const float* g1_w   = (const float*)d_in[19];
  const float* g1_ew  = (const float*)d_in[20];
  const float* g1_as  = (const float*)d_in[21];
  const float* g1_ad  = (const float*)d_in[22];
  const float* g1_ae  = (const float*)d_in[23];
  const float* g1_b   = (const float*)d_in[24];
  const float* ln1_g  = (const float*)d_in[25];
  const float* ln1_b  = (const float*)d_in[26];
  const float* g2_w   = (const float*)d_in[27];
  const float* g2_ew  = (const float*)d_in[28];
  const float* g2_as  = (const float*)d_in[29];
  const float* g2_ad  = (const float*)d_in[30];
  const float* g2_ae  = (const float*)d_in[31];
  const float* g2_b   = (const float*)d_in[32];
  const float* ln2_g  = (const float*)d_in[33];
  const float* ln2_b  = (const float*)d_in[34];
  const float* cls_w1 = (const float*)d_in[35];
  const float* cls_b1 = (const float*)d_in[36];
  const float* cls_w2 = (const float*)d_in[37];
  const float* cls_b2 = (const float*)d_in[38];
  float* outp = (float*)d_out;

  const int N = N_NODES, E = N_EDGES;

  // bump allocator on d_ws (256B aligned)
  char* base = (char*)d_ws;
  size_t o = 0;
  auto alloc = [&](size_t bytes)->void*{
    void* p = base + o;
    o += (bytes + 255) & ~(size_t)255;
    return p;
  };
  float* hA        = (float*)alloc((size_t)N*1024*4);
  float* hB        = (float*)alloc((size_t)N*1024*4);
  float* als       = (float*)alloc((size_t)N*4*4);
  float* ald       = (float*)alloc((size_t)N*4*4);
  float* scores    = (float*)alloc((size_t)N*4);
  float* wts       = (float*)alloc((size_t)N*4);
  int*   cnt       = (int*)  alloc((size_t)N*4);
  float* easum     = (float*)alloc((size_t)N*4);
  int*   off       = (int*)  alloc((size_t)(N+1)*4);
  int*   fill      = (int*)  alloc((size_t)N*4);
  int*   csr_src   = (int*)  alloc((size_t)E*4);
  float* csr_ea    = (float*)alloc((size_t)E*4);
  float* loop_attr = (float*)alloc((size_t)N*4);
  float* Kv        = (float*)alloc(256*4);
  float* Vv        = (float*)alloc(256*4);
  float* qK        = (float*)alloc(1280*4);
  float* Vo        = (float*)alloc(1280*4);
  float* obW       = (float*)alloc(1024*4);
  float* VoW       = (float*)alloc(1024*4);
  float* web       = (float*)alloc(16*4);
  float* gsum      = (float*)alloc(256*4);

  // zero the atomically-accumulated buffers (ws is poisoned 0xAA each call)
  hipMemsetAsync(cnt,   0, (size_t)N*4, stream);
  hipMemsetAsync(easum, 0, (size_t)N*4, stream);
  hipMemsetAsync(fill,  0, (size_t)N*4, stream);
  hipMemsetAsync(gsum,  0, 256*4,       stream);

  // ---- edge preprocessing (CSR by dst, reused by all 3 layers) ----
  int eblocks = (E + 255)/256;
  edge_count_kernel<<<eblocks,256,0,stream>>>(ei, ea, cnt, easum, E);
  scan_kernel<<<1,1024,0,stream>>>(cnt, easum, off, loop_attr, N);
  edge_fill_kernel<<<eblocks,256,0,stream>>>(ei, ea, off, fill, csr_src, csr_ea, E);

  // ---- cross-attention, collapsed to rank-1 ----
  kv_kernel<<<1,256,0,stream>>>(x, ca_kw, ca_kb, ca_vw, ca_vb, Kv, Vv);
  qkvo_kernel<<<10,256,0,stream>>>(ca_qw, ca_ow, Kv, Vv, qK, Vo);
  obw_kernel<<<4,256,0,stream>>>(ca_ob, Vo, g0_w, obW, VoW);
  scores_kernel<<<(N+3)/4,256,0,stream>>>(x, qK, scores, N);
  softmax_nodes<<<1,1024,0,stream>>>(scores, wts, N);

  // ---- layer 0: GEMM(xe @ g0_w) + rank-1 epilogue -> hA ----
  sgemm128<<<dim3((N+127)/128, 1024/128),256,0,stream>>>(
      x, XROW, g0_w, 1024, hA, 1024, N, 1280, obW, VoW, wts);
  alsd_kernel<4><<<N,256,0,stream>>>(hA, g0_as, g0_ad, als, ald, N);
  we_kernel<4><<<1,256,0,stream>>>(g0_ew, g0_ae, web);
  gat_agg_ln<4><<<N,256,0,stream>>>(hA, als, ald, off, csr_src, csr_ea, loop_attr,
                                    web, g0_b, ln0_g, ln0_b, hB);

  // ---- layer 1 ----
  sgemm128<<<dim3((N+127)/128, 1024/128),256,0,stream>>>(
      hB, 1024, g1_w, 1024, hA, 1024, N, 1024, nullptr, nullptr, nullptr);
  alsd_kernel<4><<<N,256,0,stream>>>(hA, g1_as, g1_ad, als, ald, N);
  we_kernel<4><<<1,256,0,stream>>>(g1_ew, g1_ae, web);
  gat_agg_ln<4><<<N,256,0,stream>>>(hA, als, ald, off, csr_src, csr_ea, loop_attr,
                                    web, g1_b, ln1_g, ln1_b, hB);

  // ---- layer 2 (1 head, 256 out) ----
  sgemm128<<<dim3((N+127)/128, 256/128),256,0,stream>>>(
      hB, 1024, g2_w, 256, hA, 256, N, 1024, nullptr, nullptr, nullptr);
  alsd_kernel<1><<<(N+3)/4,256,0,stream>>>(hA, g2_as, g2_ad, als, ald, N);
  we_kernel<1><<<1,256,0,stream>>>(g2_ew, g2_ae, web);
  gat_agg_ln<1><<<N,256,0,stream>>>(hA, als, ald, off, csr_src, csr_ea, loop_attr,
                                    web, g2_b, ln2_g, ln2_b, hB);

  // ---- mean pool + classifier ----
  colsum_kernel<<<256,256,0,stream>>>(hB, gsum, N);
  cls_kernel<<<1,128,0,stream>>>(gsum, cls_w1, cls_b1, cls_w2, cls_b2, outp);

  (void)in_sizes; (void)n_in; (void)out_size; (void)ws_size;
}

// Round 2
// 1197.439 us; speedup vs baseline: 1.9885x; 1.9885x over previous
//
#include <hip/hip_runtime.h>
#include <hip/hip_bf16.h>
#include <math.h>

#define N_NODES 20000
#define N_EDGES 200000
#define XROW    1480   // EMB + MD

typedef __attribute__((ext_vector_type(8))) short bf16x8;
typedef __attribute__((ext_vector_type(4))) float f32x4v;

// ---------------- reduction helpers ----------------
__device__ __forceinline__ float wsum(float v){
#pragma unroll
  for (int o=32;o>0;o>>=1) v += __shfl_down(v,o);
  return v;
}
__device__ __forceinline__ float wmax(float v){
#pragma unroll
  for (int o=32;o>0;o>>=1) v = fmaxf(v,__shfl_down(v,o));
  return v;
}
__device__ __forceinline__ float bsum256(float v, float* red){
  int t=threadIdx.x;
  v = wsum(v);
  __syncthreads();
  if ((t&63)==0) red[t>>6]=v;
  __syncthreads();
  return red[0]+red[1]+red[2]+red[3];
}
__device__ __forceinline__ float bmax256(float v, float* red){
  int t=threadIdx.x;
  v = wmax(v);
  __syncthreads();
  if ((t&63)==0) red[t>>6]=v;
  __syncthreads();
  return fmaxf(fmaxf(red[0],red[1]),fmaxf(red[2],red[3]));
}

__device__ __forceinline__ unsigned short f2bfu(float f){
  __hip_bfloat16 h = __float2bfloat16(f);
  return *reinterpret_cast<unsigned short*>(&h);
}
__device__ __forceinline__ float bfu2f(unsigned short u){
  __hip_bfloat16 h = *reinterpret_cast<__hip_bfloat16*>(&u);
  return __bfloat162float(h);
}

__device__ __forceinline__ void async_copy16(void* lds, const void* g){
  __builtin_amdgcn_global_load_lds((const __attribute__((address_space(1))) void*)g,
                                   (__attribute__((address_space(3))) void*)lds, 16, 0, 0);
}

// ---------------- edge preprocessing (once, reused 3 layers) ----------------
__global__ void edge_count_kernel(const int* __restrict__ ei, const float* __restrict__ ea,
                                  int* __restrict__ cnt, float* __restrict__ easum, int E){
  int e = blockIdx.x*256 + threadIdx.x;
  if (e >= E) return;
  int dst = ei[E + e];
  atomicAdd(&cnt[dst], 1);
  atomicAdd(&easum[dst], ea[e]);
}

__launch_bounds__(1024)
__global__ void scan_kernel(const int* __restrict__ cnt, const float* __restrict__ easum,
                            int* __restrict__ off, float* __restrict__ loop_attr, int n){
  __shared__ int buf[1024];
  __shared__ int carry_s;
  if (threadIdx.x==0) carry_s = 0;
  __syncthreads();
  for (int base=0; base<n; base+=1024){
    int i = base + threadIdx.x;
    int v = (i<n)? cnt[i] : 0;
    if (i<n){
      loop_attr[i] = (v>0) ? easum[i]/(float)v : 0.f;  // fill='mean'
    }
    buf[threadIdx.x] = v;
    __syncthreads();
    for (int d2=1; d2<1024; d2<<=1){
      int tv = (threadIdx.x>=d2)? buf[threadIdx.x-d2] : 0;
      __syncthreads();
      buf[threadIdx.x] += tv;
      __syncthreads();
    }
    if (i<n) off[i] = carry_s + buf[threadIdx.x] - v;   // exclusive
    int tot = buf[1023];
    __syncthreads();
    if (threadIdx.x==0) carry_s += tot;
    __syncthreads();
  }
  if (threadIdx.x==0) off[n] = carry_s;
}

__global__ void edge_fill_kernel(const int* __restrict__ ei, const float* __restrict__ ea,
                                 const int* __restrict__ off, int* __restrict__ fill,
                                 int* __restrict__ csr_src, float* __restrict__ csr_ea, int E){
  int e = blockIdx.x*256 + threadIdx.x;
  if (e >= E) return;
  int dst = ei[E + e];
  int pos = off[dst] + atomicAdd(&fill[dst], 1);
  csr_src[pos] = ei[e];
  csr_ea[pos]  = ea[e];
}

// ---------------- conversions ----------------
// x[:, :1280] f32 -> bf16 (row-major, stride 1280)
__global__ void x_to_bf16(const float* __restrict__ x, unsigned short* __restrict__ xb){
  const int CH4 = 1280/4; // 320 float4 per row
  long total = (long)N_NODES*CH4;
  for (long i = (long)blockIdx.x*256 + threadIdx.x; i < total; i += (long)gridDim.x*256){
    int row = (int)(i / CH4), c4 = (int)(i % CH4);
    float4 v = *(const float4*)(x + (size_t)row*XROW + c4*4);
    ushort4 o;
    o.x = f2bfu(v.x); o.y = f2bfu(v.y); o.z = f2bfu(v.z); o.w = f2bfu(v.w);
    *(ushort4*)(xb + (size_t)row*1280 + c4*4) = o;
  }
}

// transpose + hi/lo split: W[K,N] f32 -> Whi[N,K], Wlo[N,K] bf16
__global__ void wsplit_kernel(const float* __restrict__ W, int K, int N,
                              unsigned short* __restrict__ Whi, unsigned short* __restrict__ Wlo){
  __shared__ float tile[32][33];
  int k0 = blockIdx.x*32, n0 = blockIdx.y*32;
  int tx = threadIdx.x & 31, ty = threadIdx.x >> 5; // 32 x 8
  for (int r=ty; r<32; r+=8) tile[r][tx] = W[(size_t)(k0+r)*N + n0+tx];
  __syncthreads();
  for (int r=ty; r<32; r+=8){
    float w = tile[tx][r];               // = W[k0+tx][n0+r]
    unsigned short hi = f2bfu(w);
    float rem = w - bfu2f(hi);
    unsigned short lo = f2bfu(rem);
    size_t o = (size_t)(n0+r)*K + k0+tx; // Wt[n][k]
    Whi[o] = hi; Wlo[o] = lo;
  }
}

// ---------------- cross-attention (rank-1 collapsed) ----------------
__global__ void kv_kernel(const float* __restrict__ x,
                          const float* __restrict__ kw, const float* __restrict__ kb,
                          const float* __restrict__ vw, const float* __restrict__ vb,
                          float* __restrict__ Kv, float* __restrict__ Vv){
  int j = threadIdx.x; // 256
  float ka = kb[j], va = vb[j];
  for (int k=0;k<200;k++){
    float m = x[1280+k];
    ka = fmaf(m, kw[k*256+j], ka);
    va = fmaf(m, vw[k*256+j], va);
  }
  Kv[j]=ka; Vv[j]=va;
}

__global__ void qkvo_kernel(const float* __restrict__ qw, const float* __restrict__ ow,
                            const float* __restrict__ Kv, const float* __restrict__ Vv,
                            float* __restrict__ qK, float* __restrict__ Vo){
  int idx = blockIdx.x*256 + threadIdx.x;
  if (idx < 1280){
    float a=0;
    for (int j=0;j<256;j++) a = fmaf(qw[idx*256+j], Kv[j], a);
    qK[idx]=a;
  } else if (idx < 2560){
    int j = idx-1280;
    float a=0;
    for (int i=0;i<256;i++) a = fmaf(Vv[i], ow[(size_t)i*1280+j], a);
    Vo[j]=a;
  }
}

__global__ void obw_kernel(const float* __restrict__ ob, const float* __restrict__ Vo,
                           const float* __restrict__ W, float* __restrict__ obW, float* __restrict__ VoW){
  int j = blockIdx.x*256 + threadIdx.x; // < 1024
  float a=0,b=0;
  for (int i=0;i<1280;i++){
    float w = W[(size_t)i*1024+j];
    a = fmaf(ob[i], w, a);
    b = fmaf(Vo[i], w, b);
  }
  obW[j]=a; VoW[j]=b;
}

__launch_bounds__(256)
__global__ void scores_kernel(const float* __restrict__ x, const float* __restrict__ qK,
                              float* __restrict__ scores, int n){
  __shared__ float qs[1280];
  int t = threadIdx.x;
  for (int i=t;i<1280;i+=256) qs[i]=qK[i];
  __syncthreads();
  int wid = t>>6, lane = t&63;
  int node = blockIdx.x*4 + wid;
  if (node >= n) return;
  const float4* row = (const float4*)(x + (size_t)node*XROW);
  float acc = 0;
#pragma unroll
  for (int it=0; it<5; it++){
    float4 v = row[lane + 64*it];
    float4 q = *(const float4*)&qs[4*(lane+64*it)];
    acc += v.x*q.x + v.y*q.y + v.z*q.z + v.w*q.w;
  }
  acc = wsum(acc);
  if (lane==0) scores[node] = acc;
}

__launch_bounds__(1024)
__global__ void softmax_nodes(const float* __restrict__ scores, float* __restrict__ wts, int n){
  __shared__ float red[16];
  int t = threadIdx.x, lane=t&63, wid=t>>6;
  float m = -INFINITY;
  for (int i=t;i<n;i+=1024) m = fmaxf(m, scores[i]);
  m = wmax(m);
  if (lane==0) red[wid]=m;
  __syncthreads();
  if (t==0){ float r=red[0]; for (int k=1;k<16;k++) r=fmaxf(r,red[k]); red[0]=r; }
  __syncthreads();
  float M = red[0];
  __syncthreads();
  float z=0;
  for (int i=t;i<n;i+=1024) z += expf((scores[i]-M)*(1.f/16.f));
  z = wsum(z);
  if (lane==0) red[wid]=z;
  __syncthreads();
  if (t==0){ float r=0; for (int k=0;k<16;k++) r+=red[k]; red[0]=r; }
  __syncthreads();
  float invZ = 1.f/red[0];
  for (int i=t;i<n;i+=1024) wts[i] = expf((scores[i]-M)*(1.f/16.f))*invZ;
}

// ---------------- bf16 MFMA GEMM (TN): C[M,N] = A[M,K] @ (Bhi+Blo)[N,K]^T ----------------
// 128x128 tile, BK=64, 256 threads (4 waves, 2x2 of 64x64), 16x16x32 MFMA.
// LDS staged via global_load_lds width=16 with XOR swizzle on 16B chunks.
__launch_bounds__(256)
__global__ void gemm_bf16(const unsigned short* __restrict__ A,
                          const unsigned short* __restrict__ Bhi,
                          const unsigned short* __restrict__ Blo,
                          float* __restrict__ C, int M, int N, int K,
                          const float* __restrict__ addCol,   // obW or null
                          const float* __restrict__ vCol,     // VoW
                          const float* __restrict__ wRow)     // wts
{
  __shared__ short lds[3*128*64];
  short* As = lds;
  short* Bh = lds + 128*64;
  short* Bl = lds + 2*128*64;

  const int t = threadIdx.x;
  const int w = t>>6, l = t&63;
  const int bm = blockIdx.x*128, bn = blockIdx.y*128;
  const int wr = (w>>1)*64, wc = (w&1)*64;

  f32x4v acc[4][4];
#pragma unroll
  for (int i=0;i<4;i++)
#pragma unroll
    for (int j=0;j<4;j++) acc[i][j] = (f32x4v){0.f,0.f,0.f,0.f};

  // staging geometry: phys 16B-chunk p in [0,1024) per tile; 4 issues/wave
  const unsigned short* Ap[4]; const unsigned short* Bhp[4]; const unsigned short* Blp[4];
  int ldsOff[4];
#pragma unroll
  for (int q=0;q<4;q++){
    int p  = (w*4+q)*64 + l;       // phys chunk
    int r  = p>>3, pc = p&7;
    int kc = (pc ^ (r&7))*8;       // logical k element offset
    int rowA = bm + r; if (rowA > M-1) rowA = M-1;
    Ap[q]  = A   + (size_t)rowA*K + kc;
    Bhp[q] = Bhi + (size_t)(bn+r)*K + kc;
    Blp[q] = Blo + (size_t)(bn+r)*K + kc;
    ldsOff[q] = (w*4+q)*64*8;      // shorts (wave-uniform base; lane spreads x16B)
  }

  for (int k0=0; k0<K; k0+=64){
#pragma unroll
    for (int q=0;q<4;q++) async_copy16(As + ldsOff[q], Ap[q] + k0);
#pragma unroll
    for (int q=0;q<4;q++) async_copy16(Bh + ldsOff[q], Bhp[q] + k0);
#pragma unroll
    for (int q=0;q<4;q++) async_copy16(Bl + ldsOff[q], Blp[q] + k0);
    __syncthreads();

    const int q4 = l>>4, m16 = l&15;
#pragma unroll
    for (int ks=0; ks<2; ks++){
      bf16x8 af[4], bhf[4], blf[4];
      const int c = ks*4 + q4;
#pragma unroll
      for (int i=0;i<4;i++){
        int ra = wr + i*16 + m16;
        af[i]  = *(const bf16x8*)&As[ra*64 + ((c ^ (ra&7))*8)];
        int rb = wc + i*16 + m16;
        bhf[i] = *(const bf16x8*)&Bh[rb*64 + ((c ^ (rb&7))*8)];
        blf[i] = *(const bf16x8*)&Bl[rb*64 + ((c ^ (rb&7))*8)];
      }
#pragma unroll
      for (int i=0;i<4;i++)
#pragma unroll
        for (int j=0;j<4;j++){
          acc[i][j] = __builtin_amdgcn_mfma_f32_16x16x32_bf16(af[i], bhf[j], acc[i][j], 0,0,0);
          acc[i][j] = __builtin_amdgcn_mfma_f32_16x16x32_bf16(af[i], blf[j], acc[i][j], 0,0,0);
        }
    }
    __syncthreads();
  }

  // epilogue: C/D layout col = l&15, row = (l>>4)*4 + r
  const int q4 = l>>4, m16 = l&15;
#pragma unroll
  for (int i=0;i<4;i++){
#pragma unroll
    for (int r=0;r<4;r++){
      int m = bm + wr + i*16 + q4*4 + r;
      if (m >= M) continue;
      float wrow = addCol ? wRow[m] : 0.f;
      float* crow = C + (size_t)m*N;
#pragma unroll
      for (int j=0;j<4;j++){
        int n = bn + wc + j*16 + m16;
        float v = acc[i][j][r];
        if (addCol) v += addCol[n] + wrow*vCol[n];
        crow[n] = v;
      }
    }
  }
}

// ---------------- attention logits per node/head ----------------
template<int H>
__launch_bounds__(256)
__global__ void alsd_kernel(const float* __restrict__ h,
                            const float* __restrict__ a_src, const float* __restrict__ a_dst,
                            float* __restrict__ als, float* __restrict__ ald, int n){
  int gw = (blockIdx.x*256 + threadIdx.x) >> 6;
  int lane = threadIdx.x & 63;
  if (gw >= n*H) return;
  int node = gw / H, hd = gw % H;
  const float4* row = (const float4*)(h + (size_t)node*(256*H) + hd*256);
  const float4* as  = (const float4*)(a_src + hd*256);
  const float4* ad  = (const float4*)(a_dst + hd*256);
  float4 r = row[lane], a = as[lane], b = ad[lane];
  float s = r.x*a.x + r.y*a.y + r.z*a.z + r.w*a.w;
  float d = r.x*b.x + r.y*b.y + r.z*b.z + r.w*b.w;
  s = wsum(s); d = wsum(d);
  if (lane==0){ als[(size_t)node*H+hd]=s; ald[(size_t)node*H+hd]=d; }
}

template<int H>
__global__ void we_kernel(const float* __restrict__ We, const float* __restrict__ a_edge,
                          float* __restrict__ we){
  int wid = threadIdx.x>>6, lane = threadIdx.x&63;
  if (wid < H){
    const float4* w4 = (const float4*)(We + wid*256);
    const float4* a4 = (const float4*)(a_edge + wid*256);
    float4 a = w4[lane], b = a4[lane];
    float v = a.x*b.x + a.y*b.y + a.z*b.z + a.w*b.w;
    v = wsum(v);
    if (lane==0) we[wid]=v;
  }
}

// ---------------- fused alpha-softmax + aggregate + bias + LN + ReLU ----------------
// outb != null -> write bf16 (feeds next GEMM); else write f32 to outf.
template<int H>
__launch_bounds__(256)
__global__ void gat_agg_ln(const float* __restrict__ h,
                           const float* __restrict__ als, const float* __restrict__ ald,
                           const int* __restrict__ off, const int* __restrict__ csr_src,
                           const float* __restrict__ csr_ea, const float* __restrict__ loop_attr,
                           const float* __restrict__ we,
                           const float* __restrict__ bias,
                           const float* __restrict__ ln_g, const float* __restrict__ ln_b,
                           float* __restrict__ outf, unsigned short* __restrict__ outb)
{
  constexpr int OUT = 256*H;
  const int i = blockIdx.x;
  const int t = threadIdx.x;
  __shared__ float red[4];
  __shared__ float w_lds[64*H];
  __shared__ int   src_lds[64];

  const int begin = off[i];
  const int deg   = off[i+1]-begin;
  const int S     = deg + 1;           // + self-loop

  float aldi[H], wei[H];
#pragma unroll
  for (int hh=0;hh<H;hh++){ aldi[hh]=ald[(size_t)i*H+hh]; wei[hh]=we[hh]; }
  const float lea = loop_attr[i];

  float tm[H];
#pragma unroll
  for (int hh=0;hh<H;hh++) tm[hh] = -INFINITY;
  for (int s=t; s<S; s+=256){
    int src  = (s<deg)? csr_src[begin+s] : i;
    float ev = (s<deg)? csr_ea[begin+s]  : lea;
#pragma unroll
    for (int hh=0;hh<H;hh++){
      float a = als[(size_t)src*H+hh] + aldi[hh] + ev*wei[hh];
      a = a>0.f ? a : 0.2f*a;
      tm[hh] = fmaxf(tm[hh], a);
    }
  }
  float M[H];
#pragma unroll
  for (int hh=0;hh<H;hh++) M[hh] = bmax256(tm[hh], red);

  float ts[H];
#pragma unroll
  for (int hh=0;hh<H;hh++) ts[hh]=0.f;
  for (int s=t; s<S; s+=256){
    int src  = (s<deg)? csr_src[begin+s] : i;
    float ev = (s<deg)? csr_ea[begin+s]  : lea;
#pragma unroll
    for (int hh=0;hh<H;hh++){
      float a = als[(size_t)src*H+hh] + aldi[hh] + ev*wei[hh];
      a = a>0.f ? a : 0.2f*a;
      ts[hh] += expf(a - M[hh]);
    }
  }
  float invS[H];
#pragma unroll
  for (int hh=0;hh<H;hh++){
    float ssum = bsum256(ts[hh], red);
    invS[hh] = 1.f/(ssum + 1e-16f);
  }

  const int ht = (t*H)>>8;
  float acc[H];
#pragma unroll
  for (int p=0;p<H;p++) acc[p]=0.f;

  for (int cb=0; cb<S; cb+=64){
    int m = min(64, S-cb);
    __syncthreads();
    if (t < m){
      int s = cb + t;
      int src  = (s<deg)? csr_src[begin+s] : i;
      float ev = (s<deg)? csr_ea[begin+s]  : lea;
      src_lds[t] = src;
#pragma unroll
      for (int hh=0;hh<H;hh++){
        float a = als[(size_t)src*H+hh] + aldi[hh] + ev*wei[hh];
        a = a>0.f ? a : 0.2f*a;
        w_lds[t*H+hh] = expf(a - M[hh]) * invS[hh];
      }
    }
    __syncthreads();
    for (int j=0;j<m;j++){
      const float* row = h + (size_t)src_lds[j]*OUT;
      float w = w_lds[j*H + ht];
      if constexpr (H==4){
        float4 r = *(const float4*)(row + 4*t);
        acc[0] = fmaf(w, r.x, acc[0]);
        acc[1] = fmaf(w, r.y, acc[1]);
        acc[2] = fmaf(w, r.z, acc[2]);
        acc[3] = fmaf(w, r.w, acc[3]);
      } else {
        acc[0] = fmaf(w, row[t], acc[0]);
      }
    }
  }

  const int c0 = t*H;
  float vals[H];
  if constexpr (H==4){
    float4 b4 = *(const float4*)(bias + c0);
    vals[0]=acc[0]+b4.x; vals[1]=acc[1]+b4.y; vals[2]=acc[2]+b4.z; vals[3]=acc[3]+b4.w;
  } else {
    vals[0] = acc[0] + bias[c0];
  }
  float ls=0;
#pragma unroll
  for (int p=0;p<H;p++) ls += vals[p];
  float mu = bsum256(ls, red) * (1.f/OUT);
  float lv=0;
#pragma unroll
  for (int p=0;p<H;p++){ float d=vals[p]-mu; lv += d*d; }
  float var = bsum256(lv, red) * (1.f/OUT);
  float inv = rsqrtf(var + 1e-5f);

  if constexpr (H==4){
    float4 g4 = *(const float4*)(ln_g + c0);
    float4 b4 = *(const float4*)(ln_b + c0);
    float o0 = fmaxf((vals[0]-mu)*inv*g4.x + b4.x, 0.f);
    float o1 = fmaxf((vals[1]-mu)*inv*g4.y + b4.y, 0.f);
    float o2 = fmaxf((vals[2]-mu)*inv*g4.z + b4.z, 0.f);
    float o3 = fmaxf((vals[3]-mu)*inv*g4.w + b4.w, 0.f);
    if (outb){
      ushort4 o;
      o.x=f2bfu(o0); o.y=f2bfu(o1); o.z=f2bfu(o2); o.w=f2bfu(o3);
      *(ushort4*)(outb + (size_t)i*OUT + c0) = o;
    } else {
      *(float4*)(outf + (size_t)i*OUT + c0) = make_float4(o0,o1,o2,o3);
    }
  } else {
    float y = fmaxf((vals[0]-mu)*inv*ln_g[c0] + ln_b[c0], 0.f);
    if (outb) outb[(size_t)i*OUT + c0] = f2bfu(y);
    else      outf[(size_t)i*OUT + c0] = y;
  }
}

// ---------------- mean pool + classifier ----------------
__global__ void colsum_kernel(const float* __restrict__ h2, float* __restrict__ gsum, int n){
  int c = threadIdx.x; // 256
  float acc=0;
  for (int i=blockIdx.x;i<n;i+=gridDim.x) acc += h2[(size_t)i*256 + c];
  atomicAdd(&gsum[c], acc);
}

__launch_bounds__(128)
__global__ void cls_kernel(const float* __restrict__ gsum,
                           const float* __restrict__ w1, const float* __restrict__ b1,
                           const float* __restrict__ w2, const float* __restrict__ b2,
                           float* __restrict__ outp){
  __shared__ float g[256];
  __shared__ float hid[128];
  int t = threadIdx.x;
  g[t]     = gsum[t]    *(1.f/N_NODES);
  g[t+128] = gsum[t+128]*(1.f/N_NODES);
  __syncthreads();
  float a = b1[t];
  for (int c=0;c<256;c++) a = fmaf(g[c], w1[c*128+t], a);
  hid[t] = fmaxf(a, 0.f);
  __syncthreads();
  if (t<2){
    float o = b2[t];
    for (int j=0;j<128;j++) o = fmaf(hid[j], w2[j*2+t], o);
    outp[t] = o;
  }
}

// ---------------- launch ----------------
extern "C" void kernel_launch(void* const* d_in, const int* in_sizes, int n_in,
                              void* d_out, int out_size, void* d_ws, size_t ws_size,
                              hipStream_t stream)
{
  const float* x      = (const float*)d_in[0];
  const int*   ei     = (const int*)  d_in[1];
  const float* ea     = (const float*)d_in[2];
  const float* ca_qw  = (const float*)d_in[3];
  const float* ca_kw  = (const float*)d_in[5];
  const float* ca_kb  = (const float*)d_in[6];
  const float* ca_vw  = (const float*)d_in[7];
  const float* ca_vb  = (const float*)d_in[8];
  const float* ca_ow  = (const float*)d_in[9];
  const float* ca_ob  = (const float*)d_in[10];
  const float* g0_w   = (const float*)d_in[11];
  const float* g0_ew  = (const float*)d_in[12];
  const float* g0_as  = (const float*)d_in[13];
  const float* g0_ad  = (const float*)d_in[14];
  const float* g0_ae  = (const float*)d_in[15];
  const float* g0_b   = (const float*)d_in[16];
  const float* ln0_g  = (const float*)d_in[17];
  const float* ln0_b  = (const float*)d_in[18];
  const float* g1_w   = (const float*)d_in[19];
  const float* g1_ew  = (const float*)d_in[20];
  const float* g1_as  = (const float*)d_in[21];
  const float* g1_ad  = (const float*)d_in[22];
  const float* g1_ae  = (const float*)d_in[23];
  const float* g1_b   = (const float*)d_in[24];
  const float* ln1_g  = (const float*)d_in[25];
  const float* ln1_b  = (const float*)d_in[26];
  const float* g2_w   = (const float*)d_in[27];
  const float* g2_ew  = (const float*)d_in[28];
  const float* g2_as  = (const float*)d_in[29];
  const float* g2_ad  = (const float*)d_in[30];
  const float* g2_ae  = (const float*)d_in[31];
  const float* g2_b   = (const float*)d_in[32];
  const float* ln2_g  = (const float*)d_in[33];
  const float* ln2_b  = (const float*)d_in[34];
  const float* cls_w1 = (const float*)d_in[35];
  const float* cls_b1 = (const float*)d_in[36];
  const float* cls_w2 = (const float*)d_in[37];
  const float* cls_b2 = (const float*)d_in[38];
  float* outp = (float*)d_out;

  const int N = N_NODES, E = N_EDGES;

  char* base = (char*)d_ws;
  size_t o = 0;
  auto alloc = [&](size_t bytes)->void*{
    void* p = base + o;
    o += (bytes + 255) & ~(size_t)255;
    return p;
  };
  float*          hA   = (float*)         alloc((size_t)N*1024*4); // GEMM output (f32)
  unsigned short* Abf  = (unsigned short*)alloc((size_t)N*1280*2); // bf16 activations (xbf, then hB)
  float*          h2   = (float*)         alloc((size_t)N*256*4);  // layer-2 agg out (f32)
  unsigned short* Whi  = (unsigned short*)alloc((size_t)1280*1024*2);
  unsigned short* Wlo  = (unsigned short*)alloc((size_t)1280*1024*2);
  float* als       = (float*)alloc((size_t)N*4*4);
  float* ald       = (float*)alloc((size_t)N*4*4);
  float* scores    = (float*)alloc((size_t)N*4);
  float* wts       = (float*)alloc((size_t)N*4);
  int*   cnt       = (int*)  alloc((size_t)N*4);
  float* easum     = (float*)alloc((size_t)N*4);
  int*   off       = (int*)  alloc((size_t)(N+1)*4);
  int*   fill      = (int*)  alloc((size_t)N*4);
  int*   csr_src   = (int*)  alloc((size_t)E*4);
  float* csr_ea    = (float*)alloc((size_t)E*4);
  float* loop_attr = (float*)alloc((size_t)N*4);
  float* Kv        = (float*)alloc(256*4);
  float* Vv        = (float*)alloc(256*4);
  float* qK        = (float*)alloc(1280*4);
  float* Vo        = (float*)alloc(1280*4);
  float* obW       = (float*)alloc(1024*4);
  float* VoW       = (float*)alloc(1024*4);
  float* web       = (float*)alloc(16*4);
  float* gsum      = (float*)alloc(256*4);

  hipMemsetAsync(cnt,   0, (size_t)N*4, stream);
  hipMemsetAsync(easum, 0, (size_t)N*4, stream);
  hipMemsetAsync(fill,  0, (size_t)N*4, stream);
  hipMemsetAsync(gsum,  0, 256*4,       stream);

  // ---- edge preprocessing (CSR by dst) ----
  int eblocks = (E + 255)/256;
  edge_count_kernel<<<eblocks,256,0,stream>>>(ei, ea, cnt, easum, E);
  scan_kernel<<<1,1024,0,stream>>>(cnt, easum, off, loop_attr, N);
  edge_fill_kernel<<<eblocks,256,0,stream>>>(ei, ea, off, fill, csr_src, csr_ea, E);

  // ---- activations to bf16 ----
  x_to_bf16<<<2048,256,0,stream>>>(x, Abf);

  // ---- cross-attention, rank-1 collapsed ----
  kv_kernel<<<1,256,0,stream>>>(x, ca_kw, ca_kb, ca_vw, ca_vb, Kv, Vv);
  qkvo_kernel<<<10,256,0,stream>>>(ca_qw, ca_ow, Kv, Vv, qK, Vo);
  obw_kernel<<<4,256,0,stream>>>(ca_ob, Vo, g0_w, obW, VoW);
  scores_kernel<<<(N+3)/4,256,0,stream>>>(x, qK, scores, N);
  softmax_nodes<<<1,1024,0,stream>>>(scores, wts, N);

  const int MB = (N + 127)/128; // 157

  // ---- layer 0 ----
  wsplit_kernel<<<dim3(1280/32, 1024/32),256,0,stream>>>(g0_w, 1280, 1024, Whi, Wlo);
  gemm_bf16<<<dim3(MB, 1024/128),256,0,stream>>>(Abf, Whi, Wlo, hA, N, 1024, 1280, obW, VoW, wts);
  alsd_kernel<4><<<N,256,0,stream>>>(hA, g0_as, g0_ad, als, ald, N);
  we_kernel<4><<<1,256,0,stream>>>(g0_ew, g0_ae, web);
  gat_agg_ln<4><<<N,256,0,stream>>>(hA, als, ald, off, csr_src, csr_ea, loop_attr,
                                    web, g0_b, ln0_g, ln0_b, nullptr, Abf);

  // ---- layer 1 ----
  wsplit_kernel<<<dim3(1024/32, 1024/32),256,0,stream>>>(g1_w, 1024, 1024, Whi, Wlo);
  gemm_bf16<<<dim3(MB, 1024/128),256,0,stream>>>(Abf, Whi, Wlo, hA, N, 1024, 1024, nullptr, nullptr, nullptr);
  alsd_kernel<4><<<N,256,0,stream>>>(hA, g1_as, g1_ad, als, ald, N);
  we_kernel<4><<<1,256,0,stream>>>(g1_ew, g1_ae, web);
  gat_agg_ln<4><<<N,256,0,stream>>>(hA, als, ald, off, csr_src, csr_ea, loop_attr,
                                    web, g1_b, ln1_g, ln1_b, nullptr, Abf);

  // ---- layer 2 (1 head, 256 out) ----
  wsplit_kernel<<<dim3(1024/32, 256/32),256,0,stream>>>(g2_w, 1024, 256, Whi, Wlo);
  gemm_bf16<<<dim3(MB, 256/128),256,0,stream>>>(Abf, Whi, Wlo, hA, N, 256, 1024, nullptr, nullptr, nullptr);
  alsd_kernel<1><<<(N+3)/4,256,0,stream>>>(hA, g2_as, g2_ad, als, ald, N);
  we_kernel<1><<<1,256,0,stream>>>(g2_ew, g2_ae, web);
  gat_agg_ln<1><<<N,256,0,stream>>>(hA, als, ald, off, csr_src, csr_ea, loop_attr,
                                    web, g2_b, ln2_g, ln2_b, h2, nullptr);

  // ---- mean pool + classifier ----
  colsum_kernel<<<256,256,0,stream>>>(h2, gsum, N);
  cls_kernel<<<1,128,0,stream>>>(gsum, cls_w1, cls_b1, cls_w2, cls_b2, outp);

  (void)in_sizes; (void)n_in; (void)out_size; (void)ws_size;
}

// Round 3
// 1132.079 us; speedup vs baseline: 2.1034x; 1.0577x over previous
//
#include <hip/hip_runtime.h>
#include <hip/hip_bf16.h>
#include <math.h>

#define N_NODES 20000
#define N_EDGES 200000
#define XROW    1480   // EMB + MD

typedef __attribute__((ext_vector_type(8))) short bf16x8;
typedef __attribute__((ext_vector_type(4))) float f32x4v;

// ---------------- reduction helpers ----------------
__device__ __forceinline__ float wsum(float v){
#pragma unroll
  for (int o=32;o>0;o>>=1) v += __shfl_down(v,o);
  return v;
}
__device__ __forceinline__ float wmax(float v){
#pragma unroll
  for (int o=32;o>0;o>>=1) v = fmaxf(v,__shfl_down(v,o));
  return v;
}
__device__ __forceinline__ float bsum256(float v, float* red){
  int t=threadIdx.x;
  v = wsum(v);
  __syncthreads();
  if ((t&63)==0) red[t>>6]=v;
  __syncthreads();
  return red[0]+red[1]+red[2]+red[3];
}
__device__ __forceinline__ float bmax256(float v, float* red){
  int t=threadIdx.x;
  v = wmax(v);
  __syncthreads();
  if ((t&63)==0) red[t>>6]=v;
  __syncthreads();
  return fmaxf(fmaxf(red[0],red[1]),fmaxf(red[2],red[3]));
}

__device__ __forceinline__ unsigned short f2bfu(float f){
  __hip_bfloat16 h = __float2bfloat16(f);
  return *reinterpret_cast<unsigned short*>(&h);
}
__device__ __forceinline__ float bfu2f(unsigned short u){
  __hip_bfloat16 h = *reinterpret_cast<__hip_bfloat16*>(&u);
  return __bfloat162float(h);
}

__device__ __forceinline__ void async_copy16(void* lds, const void* g){
  __builtin_amdgcn_global_load_lds((const __attribute__((address_space(1))) void*)g,
                                   (__attribute__((address_space(3))) void*)lds, 16, 0, 0);
}

// ---------------- edge preprocessing (once, reused 3 layers) ----------------
__global__ void edge_count_kernel(const int* __restrict__ ei, const float* __restrict__ ea,
                                  int* __restrict__ cnt, float* __restrict__ easum, int E){
  int e = blockIdx.x*256 + threadIdx.x;
  if (e >= E) return;
  int dst = ei[E + e];
  atomicAdd(&cnt[dst], 1);
  atomicAdd(&easum[dst], ea[e]);
}

__launch_bounds__(1024)
__global__ void scan_kernel(const int* __restrict__ cnt, const float* __restrict__ easum,
                            int* __restrict__ off, float* __restrict__ loop_attr, int n){
  __shared__ int buf[1024];
  __shared__ int carry_s;
  if (threadIdx.x==0) carry_s = 0;
  __syncthreads();
  for (int base=0; base<n; base+=1024){
    int i = base + threadIdx.x;
    int v = (i<n)? cnt[i] : 0;
    if (i<n){
      loop_attr[i] = (v>0) ? easum[i]/(float)v : 0.f;  // fill='mean'
    }
    buf[threadIdx.x] = v;
    __syncthreads();
    for (int d2=1; d2<1024; d2<<=1){
      int tv = (threadIdx.x>=d2)? buf[threadIdx.x-d2] : 0;
      __syncthreads();
      buf[threadIdx.x] += tv;
      __syncthreads();
    }
    if (i<n) off[i] = carry_s + buf[threadIdx.x] - v;   // exclusive
    int tot = buf[1023];
    __syncthreads();
    if (threadIdx.x==0) carry_s += tot;
    __syncthreads();
  }
  if (threadIdx.x==0) off[n] = carry_s;
}

__global__ void edge_fill_kernel(const int* __restrict__ ei, const float* __restrict__ ea,
                                 const int* __restrict__ off, int* __restrict__ fill,
                                 int* __restrict__ csr_src, float* __restrict__ csr_ea, int E){
  int e = blockIdx.x*256 + threadIdx.x;
  if (e >= E) return;
  int dst = ei[E + e];
  int pos = off[dst] + atomicAdd(&fill[dst], 1);
  csr_src[pos] = ei[e];
  csr_ea[pos]  = ea[e];
}

// ---------------- conversions ----------------
// x[:, :1280] f32 -> bf16 (row-major, stride 1280)
__global__ void x_to_bf16(const float* __restrict__ x, unsigned short* __restrict__ xb){
  const int CH4 = 1280/4; // 320 float4 per row
  long total = (long)N_NODES*CH4;
  for (long i = (long)blockIdx.x*256 + threadIdx.x; i < total; i += (long)gridDim.x*256){
    int row = (int)(i / CH4), c4 = (int)(i % CH4);
    float4 v = *(const float4*)(x + (size_t)row*XROW + c4*4);
    ushort4 o;
    o.x = f2bfu(v.x); o.y = f2bfu(v.y); o.z = f2bfu(v.z); o.w = f2bfu(v.w);
    *(ushort4*)(xb + (size_t)row*1280 + c4*4) = o;
  }
}

// transpose + hi/lo split: W[K,N] f32 -> Whi[N,K], Wlo[N,K] bf16
__global__ void wsplit_kernel(const float* __restrict__ W, int K, int N,
                              unsigned short* __restrict__ Whi, unsigned short* __restrict__ Wlo){
  __shared__ float tile[32][33];
  int k0 = blockIdx.x*32, n0 = blockIdx.y*32;
  int tx = threadIdx.x & 31, ty = threadIdx.x >> 5; // 32 x 8
  for (int r=ty; r<32; r+=8) tile[r][tx] = W[(size_t)(k0+r)*N + n0+tx];
  __syncthreads();
  for (int r=ty; r<32; r+=8){
    float w = tile[tx][r];               // = W[k0+tx][n0+r]
    unsigned short hi = f2bfu(w);
    float rem = w - bfu2f(hi);
    unsigned short lo = f2bfu(rem);
    size_t o = (size_t)(n0+r)*K + k0+tx; // Wt[n][k]
    Whi[o] = hi; Wlo[o] = lo;
  }
}

// ---------------- cross-attention (rank-1 collapsed) ----------------
__global__ void kv_kernel(const float* __restrict__ x,
                          const float* __restrict__ kw, const float* __restrict__ kb,
                          const float* __restrict__ vw, const float* __restrict__ vb,
                          float* __restrict__ Kv, float* __restrict__ Vv){
  int j = threadIdx.x; // 256
  float ka = kb[j], va = vb[j];
  for (int k=0;k<200;k++){
    float m = x[1280+k];
    ka = fmaf(m, kw[k*256+j], ka);
    va = fmaf(m, vw[k*256+j], va);
  }
  Kv[j]=ka; Vv[j]=va;
}

__global__ void qkvo_kernel(const float* __restrict__ qw, const float* __restrict__ ow,
                            const float* __restrict__ Kv, const float* __restrict__ Vv,
                            float* __restrict__ qK, float* __restrict__ Vo){
  int idx = blockIdx.x*256 + threadIdx.x;
  if (idx < 1280){
    float a=0;
    for (int j=0;j<256;j++) a = fmaf(qw[idx*256+j], Kv[j], a);
    qK[idx]=a;
  } else if (idx < 2560){
    int j = idx-1280;
    float a=0;
    for (int i=0;i<256;i++) a = fmaf(Vv[i], ow[(size_t)i*1280+j], a);
    Vo[j]=a;
  }
}

__global__ void obw_kernel(const float* __restrict__ ob, const float* __restrict__ Vo,
                           const float* __restrict__ W, float* __restrict__ obW, float* __restrict__ VoW){
  int j = blockIdx.x*256 + threadIdx.x; // < 1024
  float a=0,b=0;
  for (int i=0;i<1280;i++){
    float w = W[(size_t)i*1024+j];
    a = fmaf(ob[i], w, a);
    b = fmaf(Vo[i], w, b);
  }
  obW[j]=a; VoW[j]=b;
}

__launch_bounds__(256)
__global__ void scores_kernel(const float* __restrict__ x, const float* __restrict__ qK,
                              float* __restrict__ scores, int n){
  __shared__ float qs[1280];
  int t = threadIdx.x;
  for (int i=t;i<1280;i+=256) qs[i]=qK[i];
  __syncthreads();
  int wid = t>>6, lane = t&63;
  int node = blockIdx.x*4 + wid;
  if (node >= n) return;
  const float4* row = (const float4*)(x + (size_t)node*XROW);
  float acc = 0;
#pragma unroll
  for (int it=0; it<5; it++){
    float4 v = row[lane + 64*it];
    float4 q = *(const float4*)&qs[4*(lane+64*it)];
    acc += v.x*q.x + v.y*q.y + v.z*q.z + v.w*q.w;
  }
  acc = wsum(acc);
  if (lane==0) scores[node] = acc;
}

__launch_bounds__(1024)
__global__ void softmax_nodes(const float* __restrict__ scores, float* __restrict__ wts, int n){
  __shared__ float red[16];
  int t = threadIdx.x, lane=t&63, wid=t>>6;
  float m = -INFINITY;
  for (int i=t;i<n;i+=1024) m = fmaxf(m, scores[i]);
  m = wmax(m);
  if (lane==0) red[wid]=m;
  __syncthreads();
  if (t==0){ float r=red[0]; for (int k=1;k<16;k++) r=fmaxf(r,red[k]); red[0]=r; }
  __syncthreads();
  float M = red[0];
  __syncthreads();
  float z=0;
  for (int i=t;i<n;i+=1024) z += expf((scores[i]-M)*(1.f/16.f));
  z = wsum(z);
  if (lane==0) red[wid]=z;
  __syncthreads();
  if (t==0){ float r=0; for (int k=0;k<16;k++) r+=red[k]; red[0]=r; }
  __syncthreads();
  float invZ = 1.f/red[0];
  for (int i=t;i<n;i+=1024) wts[i] = expf((scores[i]-M)*(1.f/16.f))*invZ;
}

// ---------------- bf16 MFMA GEMM (TN): C[M,N] = A[M,K] @ (Bhi+Blo)[N,K]^T ----------------
// 128x128 tile, BK=64, 256 threads (4 waves, 2x2 of 64x64), 16x16x32 MFMA.
// Output written as bf16 (halves downstream gather traffic).
__launch_bounds__(256)
__global__ void gemm_bf16(const unsigned short* __restrict__ A,
                          const unsigned short* __restrict__ Bhi,
                          const unsigned short* __restrict__ Blo,
                          unsigned short* __restrict__ C, int M, int N, int K,
                          const float* __restrict__ addCol,   // obW or null
                          const float* __restrict__ vCol,     // VoW
                          const float* __restrict__ wRow)     // wts
{
  __shared__ short lds[3*128*64];
  short* As = lds;
  short* Bh = lds + 128*64;
  short* Bl = lds + 2*128*64;

  const int t = threadIdx.x;
  const int w = t>>6, l = t&63;
  const int bm = blockIdx.x*128, bn = blockIdx.y*128;
  const int wr = (w>>1)*64, wc = (w&1)*64;

  f32x4v acc[4][4];
#pragma unroll
  for (int i=0;i<4;i++)
#pragma unroll
    for (int j=0;j<4;j++) acc[i][j] = (f32x4v){0.f,0.f,0.f,0.f};

  const unsigned short* Ap[4]; const unsigned short* Bhp[4]; const unsigned short* Blp[4];
  int ldsOff[4];
#pragma unroll
  for (int q=0;q<4;q++){
    int p  = (w*4+q)*64 + l;       // phys chunk
    int r  = p>>3, pc = p&7;
    int kc = (pc ^ (r&7))*8;       // logical k element offset
    int rowA = bm + r; if (rowA > M-1) rowA = M-1;
    Ap[q]  = A   + (size_t)rowA*K + kc;
    Bhp[q] = Bhi + (size_t)(bn+r)*K + kc;
    Blp[q] = Blo + (size_t)(bn+r)*K + kc;
    ldsOff[q] = (w*4+q)*64*8;      // shorts (wave-uniform base; lane spreads x16B)
  }

  for (int k0=0; k0<K; k0+=64){
#pragma unroll
    for (int q=0;q<4;q++) async_copy16(As + ldsOff[q], Ap[q] + k0);
#pragma unroll
    for (int q=0;q<4;q++) async_copy16(Bh + ldsOff[q], Bhp[q] + k0);
#pragma unroll
    for (int q=0;q<4;q++) async_copy16(Bl + ldsOff[q], Blp[q] + k0);
    __syncthreads();

    const int q4 = l>>4, m16 = l&15;
#pragma unroll
    for (int ks=0; ks<2; ks++){
      bf16x8 af[4], bhf[4], blf[4];
      const int c = ks*4 + q4;
#pragma unroll
      for (int i=0;i<4;i++){
        int ra = wr + i*16 + m16;
        af[i]  = *(const bf16x8*)&As[ra*64 + ((c ^ (ra&7))*8)];
        int rb = wc + i*16 + m16;
        bhf[i] = *(const bf16x8*)&Bh[rb*64 + ((c ^ (rb&7))*8)];
        blf[i] = *(const bf16x8*)&Bl[rb*64 + ((c ^ (rb&7))*8)];
      }
#pragma unroll
      for (int i=0;i<4;i++)
#pragma unroll
        for (int j=0;j<4;j++){
          acc[i][j] = __builtin_amdgcn_mfma_f32_16x16x32_bf16(af[i], bhf[j], acc[i][j], 0,0,0);
          acc[i][j] = __builtin_amdgcn_mfma_f32_16x16x32_bf16(af[i], blf[j], acc[i][j], 0,0,0);
        }
    }
    __syncthreads();
  }

  // epilogue: C/D layout col = l&15, row = (l>>4)*4 + r ; f32 math then bf16 store
  const int q4 = l>>4, m16 = l&15;
#pragma unroll
  for (int i=0;i<4;i++){
#pragma unroll
    for (int r=0;r<4;r++){
      int m = bm + wr + i*16 + q4*4 + r;
      if (m >= M) continue;
      float wrow = addCol ? wRow[m] : 0.f;
      unsigned short* crow = C + (size_t)m*N;
#pragma unroll
      for (int j=0;j<4;j++){
        int n = bn + wc + j*16 + m16;
        float v = acc[i][j][r];
        if (addCol) v += addCol[n] + wrow*vCol[n];
        crow[n] = f2bfu(v);
      }
    }
  }
}

// ---------------- attention logits per node/head (bf16 h) ----------------
template<int H>
__launch_bounds__(256)
__global__ void alsd_kernel(const unsigned short* __restrict__ h,
                            const float* __restrict__ a_src, const float* __restrict__ a_dst,
                            float* __restrict__ als, float* __restrict__ ald, int n){
  int gw = (blockIdx.x*256 + threadIdx.x) >> 6;
  int lane = threadIdx.x & 63;
  if (gw >= n*H) return;
  int node = gw / H, hd = gw % H;
  const ushort4* row = (const ushort4*)(h + (size_t)node*(256*H) + hd*256);
  const float4* as  = (const float4*)(a_src + hd*256);
  const float4* ad  = (const float4*)(a_dst + hd*256);
  ushort4 ru = row[lane];
  float4 a = as[lane], b = ad[lane];
  float rx=bfu2f(ru.x), ry=bfu2f(ru.y), rz=bfu2f(ru.z), rw=bfu2f(ru.w);
  float s = rx*a.x + ry*a.y + rz*a.z + rw*a.w;
  float d = rx*b.x + ry*b.y + rz*b.z + rw*b.w;
  s = wsum(s); d = wsum(d);
  if (lane==0){ als[(size_t)node*H+hd]=s; ald[(size_t)node*H+hd]=d; }
}

template<int H>
__global__ void we_kernel(const float* __restrict__ We, const float* __restrict__ a_edge,
                          float* __restrict__ we){
  int wid = threadIdx.x>>6, lane = threadIdx.x&63;
  if (wid < H){
    const float4* w4 = (const float4*)(We + wid*256);
    const float4* a4 = (const float4*)(a_edge + wid*256);
    float4 a = w4[lane], b = a4[lane];
    float v = a.x*b.x + a.y*b.y + a.z*b.z + a.w*b.w;
    v = wsum(v);
    if (lane==0) we[wid]=v;
  }
}

// ---------------- fused alpha-softmax + aggregate + bias + LN + ReLU ----------------
// h is bf16. outb != null -> write bf16 (feeds next GEMM); else f32 to outf.
template<int H>
__launch_bounds__(256)
__global__ void gat_agg_ln(const unsigned short* __restrict__ h,
                           const float* __restrict__ als, const float* __restrict__ ald,
                           const int* __restrict__ off, const int* __restrict__ csr_src,
                           const float* __restrict__ csr_ea, const float* __restrict__ loop_attr,
                           const float* __restrict__ we,
                           const float* __restrict__ bias,
                           const float* __restrict__ ln_g, const float* __restrict__ ln_b,
                           float* __restrict__ outf, unsigned short* __restrict__ outb)
{
  constexpr int OUT = 256*H;
  const int i = blockIdx.x;
  const int t = threadIdx.x;
  __shared__ float red[4];
  __shared__ float w_lds[64*H];
  __shared__ int   src_lds[64];

  const int begin = off[i];
  const int deg   = off[i+1]-begin;
  const int S     = deg + 1;           // + self-loop

  float aldi[H], wei[H];
#pragma unroll
  for (int hh=0;hh<H;hh++){ aldi[hh]=ald[(size_t)i*H+hh]; wei[hh]=we[hh]; }
  const float lea = loop_attr[i];

  float tm[H];
#pragma unroll
  for (int hh=0;hh<H;hh++) tm[hh] = -INFINITY;
  for (int s=t; s<S; s+=256){
    int src  = (s<deg)? csr_src[begin+s] : i;
    float ev = (s<deg)? csr_ea[begin+s]  : lea;
#pragma unroll
    for (int hh=0;hh<H;hh++){
      float a = als[(size_t)src*H+hh] + aldi[hh] + ev*wei[hh];
      a = a>0.f ? a : 0.2f*a;
      tm[hh] = fmaxf(tm[hh], a);
    }
  }
  float M[H];
#pragma unroll
  for (int hh=0;hh<H;hh++) M[hh] = bmax256(tm[hh], red);

  float ts[H];
#pragma unroll
  for (int hh=0;hh<H;hh++) ts[hh]=0.f;
  for (int s=t; s<S; s+=256){
    int src  = (s<deg)? csr_src[begin+s] : i;
    float ev = (s<deg)? csr_ea[begin+s]  : lea;
#pragma unroll
    for (int hh=0;hh<H;hh++){
      float a = als[(size_t)src*H+hh] + aldi[hh] + ev*wei[hh];
      a = a>0.f ? a : 0.2f*a;
      ts[hh] += expf(a - M[hh]);
    }
  }
  float invS[H];
#pragma unroll
  for (int hh=0;hh<H;hh++){
    float ssum = bsum256(ts[hh], red);
    invS[hh] = 1.f/(ssum + 1e-16f);
  }

  const int ht = (t*H)>>8;
  float acc[H];
#pragma unroll
  for (int p=0;p<H;p++) acc[p]=0.f;

  for (int cb=0; cb<S; cb+=64){
    int m = min(64, S-cb);
    __syncthreads();
    if (t < m){
      int s = cb + t;
      int src  = (s<deg)? csr_src[begin+s] : i;
      float ev = (s<deg)? csr_ea[begin+s]  : lea;
      src_lds[t] = src;
#pragma unroll
      for (int hh=0;hh<H;hh++){
        float a = als[(size_t)src*H+hh] + aldi[hh] + ev*wei[hh];
        a = a>0.f ? a : 0.2f*a;
        w_lds[t*H+hh] = expf(a - M[hh]) * invS[hh];
      }
    }
    __syncthreads();
    for (int j=0;j<m;j++){
      const unsigned short* row = h + (size_t)src_lds[j]*OUT;
      float w = w_lds[j*H + ht];
      if constexpr (H==4){
        ushort4 r4 = *(const ushort4*)(row + 4*t);
        acc[0] = fmaf(w, bfu2f(r4.x), acc[0]);
        acc[1] = fmaf(w, bfu2f(r4.y), acc[1]);
        acc[2] = fmaf(w, bfu2f(r4.z), acc[2]);
        acc[3] = fmaf(w, bfu2f(r4.w), acc[3]);
      } else {
        acc[0] = fmaf(w, bfu2f(row[t]), acc[0]);
      }
    }
  }

  const int c0 = t*H;
  float vals[H];
  if constexpr (H==4){
    float4 b4 = *(const float4*)(bias + c0);
    vals[0]=acc[0]+b4.x; vals[1]=acc[1]+b4.y; vals[2]=acc[2]+b4.z; vals[3]=acc[3]+b4.w;
  } else {
    vals[0] = acc[0] + bias[c0];
  }
  float ls=0;
#pragma unroll
  for (int p=0;p<H;p++) ls += vals[p];
  float mu = bsum256(ls, red) * (1.f/OUT);
  float lv=0;
#pragma unroll
  for (int p=0;p<H;p++){ float d=vals[p]-mu; lv += d*d; }
  float var = bsum256(lv, red) * (1.f/OUT);
  float inv = rsqrtf(var + 1e-5f);

  if constexpr (H==4){
    float4 g4 = *(const float4*)(ln_g + c0);
    float4 b4 = *(const float4*)(ln_b + c0);
    float o0 = fmaxf((vals[0]-mu)*inv*g4.x + b4.x, 0.f);
    float o1 = fmaxf((vals[1]-mu)*inv*g4.y + b4.y, 0.f);
    float o2 = fmaxf((vals[2]-mu)*inv*g4.z + b4.z, 0.f);
    float o3 = fmaxf((vals[3]-mu)*inv*g4.w + b4.w, 0.f);
    if (outb){
      ushort4 o;
      o.x=f2bfu(o0); o.y=f2bfu(o1); o.z=f2bfu(o2); o.w=f2bfu(o3);
      *(ushort4*)(outb + (size_t)i*OUT + c0) = o;
    } else {
      *(float4*)(outf + (size_t)i*OUT + c0) = make_float4(o0,o1,o2,o3);
    }
  } else {
    float y = fmaxf((vals[0]-mu)*inv*ln_g[c0] + ln_b[c0], 0.f);
    if (outb) outb[(size_t)i*OUT + c0] = f2bfu(y);
    else      outf[(size_t)i*OUT + c0] = y;
  }
}

// ---------------- mean pool + classifier ----------------
__global__ void colsum_kernel(const float* __restrict__ h2, float* __restrict__ gsum, int n){
  int c = threadIdx.x; // 256
  float acc=0;
  for (int i=blockIdx.x;i<n;i+=gridDim.x) acc += h2[(size_t)i*256 + c];
  atomicAdd(&gsum[c], acc);
}

__launch_bounds__(128)
__global__ void cls_kernel(const float* __restrict__ gsum,
                           const float* __restrict__ w1, const float* __restrict__ b1,
                           const float* __restrict__ w2, const float* __restrict__ b2,
                           float* __restrict__ outp){
  __shared__ float g[256];
  __shared__ float hid[128];
  int t = threadIdx.x;
  g[t]     = gsum[t]    *(1.f/N_NODES);
  g[t+128] = gsum[t+128]*(1.f/N_NODES);
  __syncthreads();
  float a = b1[t];
  for (int c=0;c<256;c++) a = fmaf(g[c], w1[c*128+t], a);
  hid[t] = fmaxf(a, 0.f);
  __syncthreads();
  if (t<2){
    float o = b2[t];
    for (int j=0;j<128;j++) o = fmaf(hid[j], w2[j*2+t], o);
    outp[t] = o;
  }
}

// ---------------- launch ----------------
extern "C" void kernel_launch(void* const* d_in, const int* in_sizes, int n_in,
                              void* d_out, int out_size, void* d_ws, size_t ws_size,
                              hipStream_t stream)
{
  const float* x      = (const float*)d_in[0];
  const int*   ei     = (const int*)  d_in[1];
  const float* ea     = (const float*)d_in[2];
  const float* ca_qw  = (const float*)d_in[3];
  const float* ca_kw  = (const float*)d_in[5];
  const float* ca_kb  = (const float*)d_in[6];
  const float* ca_vw  = (const float*)d_in[7];
  const float* ca_vb  = (const float*)d_in[8];
  const float* ca_ow  = (const float*)d_in[9];
  const float* ca_ob  = (const float*)d_in[10];
  const float* g0_w   = (const float*)d_in[11];
  const float* g0_ew  = (const float*)d_in[12];
  const float* g0_as  = (const float*)d_in[13];
  const float* g0_ad  = (const float*)d_in[14];
  const float* g0_ae  = (const float*)d_in[15];
  const float* g0_b   = (const float*)d_in[16];
  const float* ln0_g  = (const float*)d_in[17];
  const float* ln0_b  = (const float*)d_in[18];
  const float* g1_w   = (const float*)d_in[19];
  const float* g1_ew  = (const float*)d_in[20];
  const float* g1_as  = (const float*)d_in[21];
  const float* g1_ad  = (const float*)d_in[22];
  const float* g1_ae  = (const float*)d_in[23];
  const float* g1_b   = (const float*)d_in[24];
  const float* ln1_g  = (const float*)d_in[25];
  const float* ln1_b  = (const float*)d_in[26];
  const float* g2_w   = (const float*)d_in[27];
  const float* g2_ew  = (const float*)d_in[28];
  const float* g2_as  = (const float*)d_in[29];
  const float* g2_ad  = (const float*)d_in[30];
  const float* g2_ae  = (const float*)d_in[31];
  const float* g2_b   = (const float*)d_in[32];
  const float* ln2_g  = (const float*)d_in[33];
  const float* ln2_b  = (const float*)d_in[34];
  const float* cls_w1 = (const float*)d_in[35];
  const float* cls_b1 = (const float*)d_in[36];
  const float* cls_w2 = (const float*)d_in[37];
  const float* cls_b2 = (const float*)d_in[38];
  float* outp = (float*)d_out;

  const int N = N_NODES, E = N_EDGES;

  char* base = (char*)d_ws;
  size_t o = 0;
  auto alloc = [&](size_t bytes)->void*{
    void* p = base + o;
    o += (bytes + 255) & ~(size_t)255;
    return p;
  };
  unsigned short* hBf  = (unsigned short*)alloc((size_t)N*1024*2); // GEMM output h (bf16)
  unsigned short* Abf  = (unsigned short*)alloc((size_t)N*1280*2); // bf16 activations (x, then agg out)
  float*          h2   = (float*)         alloc((size_t)N*256*4);  // layer-2 agg out (f32)
  unsigned short* Whi  = (unsigned short*)alloc((size_t)1280*1024*2);
  unsigned short* Wlo  = (unsigned short*)alloc((size_t)1280*1024*2);
  float* als       = (float*)alloc((size_t)N*4*4);
  float* ald       = (float*)alloc((size_t)N*4*4);
  float* scores    = (float*)alloc((size_t)N*4);
  float* wts       = (float*)alloc((size_t)N*4);
  int*   cnt       = (int*)  alloc((size_t)N*4);
  float* easum     = (float*)alloc((size_t)N*4);
  int*   off       = (int*)  alloc((size_t)(N+1)*4);
  int*   fill      = (int*)  alloc((size_t)N*4);
  int*   csr_src   = (int*)  alloc((size_t)E*4);
  float* csr_ea    = (float*)alloc((size_t)E*4);
  float* loop_attr = (float*)alloc((size_t)N*4);
  float* Kv        = (float*)alloc(256*4);
  float* Vv        = (float*)alloc(256*4);
  float* qK        = (float*)alloc(1280*4);
  float* Vo        = (float*)alloc(1280*4);
  float* obW       = (float*)alloc(1024*4);
  float* VoW       = (float*)alloc(1024*4);
  float* web       = (float*)alloc(16*4);
  float* gsum      = (float*)alloc(256*4);

  hipMemsetAsync(cnt,   0, (size_t)N*4, stream);
  hipMemsetAsync(easum, 0, (size_t)N*4, stream);
  hipMemsetAsync(fill,  0, (size_t)N*4, stream);
  hipMemsetAsync(gsum,  0, 256*4,       stream);

  // ---- edge preprocessing (CSR by dst) ----
  int eblocks = (E + 255)/256;
  edge_count_kernel<<<eblocks,256,0,stream>>>(ei, ea, cnt, easum, E);
  scan_kernel<<<1,1024,0,stream>>>(cnt, easum, off, loop_attr, N);
  edge_fill_kernel<<<eblocks,256,0,stream>>>(ei, ea, off, fill, csr_src, csr_ea, E);

  // ---- activations to bf16 ----
  x_to_bf16<<<2048,256,0,stream>>>(x, Abf);

  // ---- cross-attention, rank-1 collapsed ----
  kv_kernel<<<1,256,0,stream>>>(x, ca_kw, ca_kb, ca_vw, ca_vb, Kv, Vv);
  qkvo_kernel<<<10,256,0,stream>>>(ca_qw, ca_ow, Kv, Vv, qK, Vo);
  obw_kernel<<<4,256,0,stream>>>(ca_ob, Vo, g0_w, obW, VoW);
  scores_kernel<<<(N+3)/4,256,0,stream>>>(x, qK, scores, N);
  softmax_nodes<<<1,1024,0,stream>>>(scores, wts, N);

  const int MB = (N + 127)/128; // 157

  // ---- layer 0 ----
  wsplit_kernel<<<dim3(1280/32, 1024/32),256,0,stream>>>(g0_w, 1280, 1024, Whi, Wlo);
  gemm_bf16<<<dim3(MB, 1024/128),256,0,stream>>>(Abf, Whi, Wlo, hBf, N, 1024, 1280, obW, VoW, wts);
  alsd_kernel<4><<<N,256,0,stream>>>(hBf, g0_as, g0_ad, als, ald, N);
  we_kernel<4><<<1,256,0,stream>>>(g0_ew, g0_ae, web);
  gat_agg_ln<4><<<N,256,0,stream>>>(hBf, als, ald, off, csr_src, csr_ea, loop_attr,
                                    web, g0_b, ln0_g, ln0_b, nullptr, Abf);

  // ---- layer 1 ----
  wsplit_kernel<<<dim3(1024/32, 1024/32),256,0,stream>>>(g1_w, 1024, 1024, Whi, Wlo);
  gemm_bf16<<<dim3(MB, 1024/128),256,0,stream>>>(Abf, Whi, Wlo, hBf, N, 1024, 1024, nullptr, nullptr, nullptr);
  alsd_kernel<4><<<N,256,0,stream>>>(hBf, g1_as, g1_ad, als, ald, N);
  we_kernel<4><<<1,256,0,stream>>>(g1_ew, g1_ae, web);
  gat_agg_ln<4><<<N,256,0,stream>>>(hBf, als, ald, off, csr_src, csr_ea, loop_attr,
                                    web, g1_b, ln1_g, ln1_b, nullptr, Abf);

  // ---- layer 2 (1 head, 256 out) ----
  wsplit_kernel<<<dim3(1024/32, 256/32),256,0,stream>>>(g2_w, 1024, 256, Whi, Wlo);
  gemm_bf16<<<dim3(MB, 256/128),256,0,stream>>>(Abf, Whi, Wlo, hBf, N, 256, 1024, nullptr, nullptr, nullptr);
  alsd_kernel<1><<<(N+3)/4,256,0,stream>>>(hBf, g2_as, g2_ad, als, ald, N);
  we_kernel<1><<<1,256,0,stream>>>(g2_ew, g2_ae, web);
  gat_agg_ln<1><<<N,256,0,stream>>>(hBf, als, ald, off, csr_src, csr_ea, loop_attr,
                                    web, g2_b, ln2_g, ln2_b, h2, nullptr);

  // ---- mean pool + classifier ----
  colsum_kernel<<<256,256,0,stream>>>(h2, gsum, N);
  cls_kernel<<<1,128,0,stream>>>(gsum, cls_w1, cls_b1, cls_w2, cls_b2, outp);

  (void)in_sizes; (void)n_in; (void)out_size; (void)ws_size;
}

// Round 4
// 1093.530 us; speedup vs baseline: 2.1775x; 1.0353x over previous
//
#include <hip/hip_runtime.h>
#include <hip/hip_bf16.h>
#include <math.h>

#define N_NODES 20000
#define N_EDGES 200000
#define XROW    1480   // EMB + MD

typedef __attribute__((ext_vector_type(8))) _Float16 f16x8;
typedef __attribute__((ext_vector_type(4))) float f32x4v;

// ---------------- reduction helpers ----------------
__device__ __forceinline__ float wsum(float v){
#pragma unroll
  for (int o=32;o>0;o>>=1) v += __shfl_down(v,o);
  return v;
}
__device__ __forceinline__ float wmax(float v){
#pragma unroll
  for (int o=32;o>0;o>>=1) v = fmaxf(v,__shfl_down(v,o));
  return v;
}
__device__ __forceinline__ float bsum256(float v, float* red){
  int t=threadIdx.x;
  v = wsum(v);
  __syncthreads();
  if ((t&63)==0) red[t>>6]=v;
  __syncthreads();
  return red[0]+red[1]+red[2]+red[3];
}
__device__ __forceinline__ float bmax256(float v, float* red){
  int t=threadIdx.x;
  v = wmax(v);
  __syncthreads();
  if ((t&63)==0) red[t>>6]=v;
  __syncthreads();
  return fmaxf(fmaxf(red[0],red[1]),fmaxf(red[2],red[3]));
}

__device__ __forceinline__ unsigned short f2hu(float f){
  _Float16 h = (_Float16)f;
  return __builtin_bit_cast(unsigned short, h);
}
__device__ __forceinline__ float hu2f(unsigned short u){
  return (float)__builtin_bit_cast(_Float16, u);
}

__device__ __forceinline__ void async_copy16(void* lds, const void* g){
  __builtin_amdgcn_global_load_lds((const __attribute__((address_space(1))) void*)g,
                                   (__attribute__((address_space(3))) void*)lds, 16, 0, 0);
}

// ---------------- edge preprocessing (once, reused 3 layers) ----------------
__global__ void edge_count_kernel(const int* __restrict__ ei, const float* __restrict__ ea,
                                  int* __restrict__ cnt, float* __restrict__ easum, int E){
  int e = blockIdx.x*256 + threadIdx.x;
  if (e >= E) return;
  int dst = ei[E + e];
  atomicAdd(&cnt[dst], 1);
  atomicAdd(&easum[dst], ea[e]);
}

__launch_bounds__(1024)
__global__ void scan_kernel(const int* __restrict__ cnt, const float* __restrict__ easum,
                            int* __restrict__ off, float* __restrict__ loop_attr, int n){
  __shared__ int buf[1024];
  __shared__ int carry_s;
  if (threadIdx.x==0) carry_s = 0;
  __syncthreads();
  for (int base=0; base<n; base+=1024){
    int i = base + threadIdx.x;
    int v = (i<n)? cnt[i] : 0;
    if (i<n){
      loop_attr[i] = (v>0) ? easum[i]/(float)v : 0.f;  // fill='mean'
    }
    buf[threadIdx.x] = v;
    __syncthreads();
    for (int d2=1; d2<1024; d2<<=1){
      int tv = (threadIdx.x>=d2)? buf[threadIdx.x-d2] : 0;
      __syncthreads();
      buf[threadIdx.x] += tv;
      __syncthreads();
    }
    if (i<n) off[i] = carry_s + buf[threadIdx.x] - v;   // exclusive
    int tot = buf[1023];
    __syncthreads();
    if (threadIdx.x==0) carry_s += tot;
    __syncthreads();
  }
  if (threadIdx.x==0) off[n] = carry_s;
}

__global__ void edge_fill_kernel(const int* __restrict__ ei, const float* __restrict__ ea,
                                 const int* __restrict__ off, int* __restrict__ fill,
                                 int* __restrict__ csr_src, float* __restrict__ csr_ea, int E){
  int e = blockIdx.x*256 + threadIdx.x;
  if (e >= E) return;
  int dst = ei[E + e];
  int pos = off[dst] + atomicAdd(&fill[dst], 1);
  csr_src[pos] = ei[e];
  csr_ea[pos]  = ea[e];
}

// ---------------- conversions ----------------
// x[:, :1280] f32 -> f16 (row-major, stride 1280)
__global__ void x_to_f16(const float* __restrict__ x, unsigned short* __restrict__ xh){
  const int CH4 = 1280/4; // 320 float4 per row
  long total = (long)N_NODES*CH4;
  for (long i = (long)blockIdx.x*256 + threadIdx.x; i < total; i += (long)gridDim.x*256){
    int row = (int)(i / CH4), c4 = (int)(i % CH4);
    float4 v = *(const float4*)(x + (size_t)row*XROW + c4*4);
    ushort4 o;
    o.x = f2hu(v.x); o.y = f2hu(v.y); o.z = f2hu(v.z); o.w = f2hu(v.w);
    *(ushort4*)(xh + (size_t)row*1280 + c4*4) = o;
  }
}

// transpose: W[K,N] f32 -> Wt[N,K] f16
__global__ void wt_f16_kernel(const float* __restrict__ W, int K, int N,
                              unsigned short* __restrict__ Wt){
  __shared__ float tile[32][33];
  int k0 = blockIdx.x*32, n0 = blockIdx.y*32;
  int tx = threadIdx.x & 31, ty = threadIdx.x >> 5; // 32 x 8
  for (int r=ty; r<32; r+=8) tile[r][tx] = W[(size_t)(k0+r)*N + n0+tx];
  __syncthreads();
  for (int r=ty; r<32; r+=8){
    float w = tile[tx][r];               // = W[k0+tx][n0+r]
    Wt[(size_t)(n0+r)*K + k0+tx] = f2hu(w);
  }
}

// ---------------- cross-attention (rank-1 collapsed) ----------------
__global__ void kv_kernel(const float* __restrict__ x,
                          const float* __restrict__ kw, const float* __restrict__ kb,
                          const float* __restrict__ vw, const float* __restrict__ vb,
                          float* __restrict__ Kv, float* __restrict__ Vv){
  int j = threadIdx.x; // 256
  float ka = kb[j], va = vb[j];
  for (int k=0;k<200;k++){
    float m = x[1280+k];
    ka = fmaf(m, kw[k*256+j], ka);
    va = fmaf(m, vw[k*256+j], va);
  }
  Kv[j]=ka; Vv[j]=va;
}

__global__ void qkvo_kernel(const float* __restrict__ qw, const float* __restrict__ ow,
                            const float* __restrict__ Kv, const float* __restrict__ Vv,
                            float* __restrict__ qK, float* __restrict__ Vo){
  int idx = blockIdx.x*256 + threadIdx.x;
  if (idx < 1280){
    float a=0;
    for (int j=0;j<256;j++) a = fmaf(qw[idx*256+j], Kv[j], a);
    qK[idx]=a;
  } else if (idx < 2560){
    int j = idx-1280;
    float a=0;
    for (int i=0;i<256;i++) a = fmaf(Vv[i], ow[(size_t)i*1280+j], a);
    Vo[j]=a;
  }
}

__global__ void obw_kernel(const float* __restrict__ ob, const float* __restrict__ Vo,
                           const float* __restrict__ W, float* __restrict__ obW, float* __restrict__ VoW){
  int j = blockIdx.x*256 + threadIdx.x; // < 1024
  float a=0,b=0;
  for (int i=0;i<1280;i++){
    float w = W[(size_t)i*1024+j];
    a = fmaf(ob[i], w, a);
    b = fmaf(Vo[i], w, b);
  }
  obW[j]=a; VoW[j]=b;
}

__launch_bounds__(256)
__global__ void scores_kernel(const float* __restrict__ x, const float* __restrict__ qK,
                              float* __restrict__ scores, int n){
  __shared__ float qs[1280];
  int t = threadIdx.x;
  for (int i=t;i<1280;i+=256) qs[i]=qK[i];
  __syncthreads();
  int wid = t>>6, lane = t&63;
  int node = blockIdx.x*4 + wid;
  if (node >= n) return;
  const float4* row = (const float4*)(x + (size_t)node*XROW);
  float acc = 0;
#pragma unroll
  for (int it=0; it<5; it++){
    float4 v = row[lane + 64*it];
    float4 q = *(const float4*)&qs[4*(lane+64*it)];
    acc += v.x*q.x + v.y*q.y + v.z*q.z + v.w*q.w;
  }
  acc = wsum(acc);
  if (lane==0) scores[node] = acc;
}

__launch_bounds__(1024)
__global__ void softmax_nodes(const float* __restrict__ scores, float* __restrict__ wts, int n){
  __shared__ float red[16];
  int t = threadIdx.x, lane=t&63, wid=t>>6;
  float m = -INFINITY;
  for (int i=t;i<n;i+=1024) m = fmaxf(m, scores[i]);
  m = wmax(m);
  if (lane==0) red[wid]=m;
  __syncthreads();
  if (t==0){ float r=red[0]; for (int k=1;k<16;k++) r=fmaxf(r,red[k]); red[0]=r; }
  __syncthreads();
  float M = red[0];
  __syncthreads();
  float z=0;
  for (int i=t;i<n;i+=1024) z += expf((scores[i]-M)*(1.f/16.f));
  z = wsum(z);
  if (lane==0) red[wid]=z;
  __syncthreads();
  if (t==0){ float r=0; for (int k=0;k<16;k++) r+=red[k]; red[0]=r; }
  __syncthreads();
  float invZ = 1.f/red[0];
  for (int i=t;i<n;i+=1024) wts[i] = expf((scores[i]-M)*(1.f/16.f))*invZ;
}

// ---------------- f16 MFMA GEMM (TN): C[M,N] = A[M,K] @ B[N,K]^T ----------------
// 128x128 tile, BK=64, 256 threads (4 waves, 2x2 of 64x64), 16x16x32 f16 MFMA.
// Output f16. Grid: (N-tiles, M-tiles) so same-A blocks dispatch together.
__launch_bounds__(256)
__global__ void gemm_f16(const unsigned short* __restrict__ A,
                         const unsigned short* __restrict__ B,
                         unsigned short* __restrict__ C, int M, int N, int K,
                         const float* __restrict__ addCol,   // obW or null
                         const float* __restrict__ vCol,     // VoW
                         const float* __restrict__ wRow)     // wts
{
  __shared__ short lds[2*128*64];
  short* As = lds;
  short* Bs = lds + 128*64;

  const int t = threadIdx.x;
  const int w = t>>6, l = t&63;
  const int bn = blockIdx.x*128, bm = blockIdx.y*128;
  const int wr = (w>>1)*64, wc = (w&1)*64;

  f32x4v acc[4][4];
#pragma unroll
  for (int i=0;i<4;i++)
#pragma unroll
    for (int j=0;j<4;j++) acc[i][j] = (f32x4v){0.f,0.f,0.f,0.f};

  const unsigned short* Ap[4]; const unsigned short* Bp[4];
  int ldsOff[4];
#pragma unroll
  for (int q=0;q<4;q++){
    int p  = (w*4+q)*64 + l;       // phys 16B-chunk
    int r  = p>>3, pc = p&7;
    int kc = (pc ^ (r&7))*8;       // logical k element offset (XOR swizzle)
    int rowA = bm + r; if (rowA > M-1) rowA = M-1;
    Ap[q] = A + (size_t)rowA*K + kc;
    Bp[q] = B + (size_t)(bn+r)*K + kc;
    ldsOff[q] = (w*4+q)*64*8;      // shorts (wave-uniform base; lane spreads x16B)
  }

  for (int k0=0; k0<K; k0+=64){
#pragma unroll
    for (int q=0;q<4;q++) async_copy16(As + ldsOff[q], Ap[q] + k0);
#pragma unroll
    for (int q=0;q<4;q++) async_copy16(Bs + ldsOff[q], Bp[q] + k0);
    __syncthreads();

    const int q4 = l>>4, m16 = l&15;
#pragma unroll
    for (int ks=0; ks<2; ks++){
      f16x8 af[4], bf[4];
      const int c = ks*4 + q4;
#pragma unroll
      for (int i=0;i<4;i++){
        int ra = wr + i*16 + m16;
        af[i] = *(const f16x8*)&As[ra*64 + ((c ^ (ra&7))*8)];
        int rb = wc + i*16 + m16;
        bf[i] = *(const f16x8*)&Bs[rb*64 + ((c ^ (rb&7))*8)];
      }
#pragma unroll
      for (int i=0;i<4;i++)
#pragma unroll
        for (int j=0;j<4;j++)
          acc[i][j] = __builtin_amdgcn_mfma_f32_16x16x32_f16(af[i], bf[j], acc[i][j], 0,0,0);
    }
    __syncthreads();
  }

  // epilogue: C/D layout col = l&15, row = (l>>4)*4 + r ; f32 math then f16 store
  const int q4 = l>>4, m16 = l&15;
#pragma unroll
  for (int i=0;i<4;i++){
#pragma unroll
    for (int r=0;r<4;r++){
      int m = bm + wr + i*16 + q4*4 + r;
      if (m >= M) continue;
      float wrow = addCol ? wRow[m] : 0.f;
      unsigned short* crow = C + (size_t)m*N;
#pragma unroll
      for (int j=0;j<4;j++){
        int n = bn + wc + j*16 + m16;
        float v = acc[i][j][r];
        if (addCol) v += addCol[n] + wrow*vCol[n];
        crow[n] = f2hu(v);
      }
    }
  }
}

// ---------------- attention logits per node/head (f16 h) ----------------
template<int H>
__launch_bounds__(256)
__global__ void alsd_kernel(const unsigned short* __restrict__ h,
                            const float* __restrict__ a_src, const float* __restrict__ a_dst,
                            float* __restrict__ als, float* __restrict__ ald, int n){
  int gw = (blockIdx.x*256 + threadIdx.x) >> 6;
  int lane = threadIdx.x & 63;
  if (gw >= n*H) return;
  int node = gw / H, hd = gw % H;
  const ushort4* row = (const ushort4*)(h + (size_t)node*(256*H) + hd*256);
  const float4* as  = (const float4*)(a_src + hd*256);
  const float4* ad  = (const float4*)(a_dst + hd*256);
  ushort4 ru = row[lane];
  float4 a = as[lane], b = ad[lane];
  float rx=hu2f(ru.x), ry=hu2f(ru.y), rz=hu2f(ru.z), rw=hu2f(ru.w);
  float s = rx*a.x + ry*a.y + rz*a.z + rw*a.w;
  float d = rx*b.x + ry*b.y + rz*b.z + rw*b.w;
  s = wsum(s); d = wsum(d);
  if (lane==0){ als[(size_t)node*H+hd]=s; ald[(size_t)node*H+hd]=d; }
}

template<int H>
__global__ void we_kernel(const float* __restrict__ We, const float* __restrict__ a_edge,
                          float* __restrict__ we){
  int wid = threadIdx.x>>6, lane = threadIdx.x&63;
  if (wid < H){
    const float4* w4 = (const float4*)(We + wid*256);
    const float4* a4 = (const float4*)(a_edge + wid*256);
    float4 a = w4[lane], b = a4[lane];
    float v = a.x*b.x + a.y*b.y + a.z*b.z + a.w*b.w;
    v = wsum(v);
    if (lane==0) we[wid]=v;
  }
}

// ---------------- fused alpha-softmax + aggregate + bias + LN + ReLU ----------------
// h is f16. outb != null -> write f16 (feeds next GEMM); else f32 to outf.
template<int H>
__launch_bounds__(256)
__global__ void gat_agg_ln(const unsigned short* __restrict__ h,
                           const float* __restrict__ als, const float* __restrict__ ald,
                           const int* __restrict__ off, const int* __restrict__ csr_src,
                           const float* __restrict__ csr_ea, const float* __restrict__ loop_attr,
                           const float* __restrict__ we,
                           const float* __restrict__ bias,
                           const float* __restrict__ ln_g, const float* __restrict__ ln_b,
                           float* __restrict__ outf, unsigned short* __restrict__ outb)
{
  constexpr int OUT = 256*H;
  const int i = blockIdx.x;
  const int t = threadIdx.x;
  __shared__ float red[4];
  __shared__ float w_lds[64*H];
  __shared__ int   src_lds[64];

  const int begin = off[i];
  const int deg   = off[i+1]-begin;
  const int S     = deg + 1;           // + self-loop

  float aldi[H], wei[H];
#pragma unroll
  for (int hh=0;hh<H;hh++){ aldi[hh]=ald[(size_t)i*H+hh]; wei[hh]=we[hh]; }
  const float lea = loop_attr[i];

  float tm[H];
#pragma unroll
  for (int hh=0;hh<H;hh++) tm[hh] = -INFINITY;
  for (int s=t; s<S; s+=256){
    int src  = (s<deg)? csr_src[begin+s] : i;
    float ev = (s<deg)? csr_ea[begin+s]  : lea;
#pragma unroll
    for (int hh=0;hh<H;hh++){
      float a = als[(size_t)src*H+hh] + aldi[hh] + ev*wei[hh];
      a = a>0.f ? a : 0.2f*a;
      tm[hh] = fmaxf(tm[hh], a);
    }
  }
  float M[H];
#pragma unroll
  for (int hh=0;hh<H;hh++) M[hh] = bmax256(tm[hh], red);

  float ts[H];
#pragma unroll
  for (int hh=0;hh<H;hh++) ts[hh]=0.f;
  for (int s=t; s<S; s+=256){
    int src  = (s<deg)? csr_src[begin+s] : i;
    float ev = (s<deg)? csr_ea[begin+s]  : lea;
#pragma unroll
    for (int hh=0;hh<H;hh++){
      float a = als[(size_t)src*H+hh] + aldi[hh] + ev*wei[hh];
      a = a>0.f ? a : 0.2f*a;
      ts[hh] += expf(a - M[hh]);
    }
  }
  float invS[H];
#pragma unroll
  for (int hh=0;hh<H;hh++){
    float ssum = bsum256(ts[hh], red);
    invS[hh] = 1.f/(ssum + 1e-16f);
  }

  const int ht = (t*H)>>8;
  float acc[H];
#pragma unroll
  for (int p=0;p<H;p++) acc[p]=0.f;

  for (int cb=0; cb<S; cb+=64){
    int m = min(64, S-cb);
    __syncthreads();
    if (t < m){
      int s = cb + t;
      int src  = (s<deg)? csr_src[begin+s] : i;
      float ev = (s<deg)? csr_ea[begin+s]  : lea;
      src_lds[t] = src;
#pragma unroll
      for (int hh=0;hh<H;hh++){
        float a = als[(size_t)src*H+hh] + aldi[hh] + ev*wei[hh];
        a = a>0.f ? a : 0.2f*a;
        w_lds[t*H+hh] = expf(a - M[hh]) * invS[hh];
      }
    }
    __syncthreads();
    for (int j=0;j<m;j++){
      const unsigned short* row = h + (size_t)src_lds[j]*OUT;
      float w = w_lds[j*H + ht];
      if constexpr (H==4){
        ushort4 r4 = *(const ushort4*)(row + 4*t);
        acc[0] = fmaf(w, hu2f(r4.x), acc[0]);
        acc[1] = fmaf(w, hu2f(r4.y), acc[1]);
        acc[2] = fmaf(w, hu2f(r4.z), acc[2]);
        acc[3] = fmaf(w, hu2f(r4.w), acc[3]);
      } else {
        acc[0] = fmaf(w, hu2f(row[t]), acc[0]);
      }
    }
  }

  const int c0 = t*H;
  float vals[H];
  if constexpr (H==4){
    float4 b4 = *(const float4*)(bias + c0);
    vals[0]=acc[0]+b4.x; vals[1]=acc[1]+b4.y; vals[2]=acc[2]+b4.z; vals[3]=acc[3]+b4.w;
  } else {
    vals[0] = acc[0] + bias[c0];
  }
  float ls=0;
#pragma unroll
  for (int p=0;p<H;p++) ls += vals[p];
  float mu = bsum256(ls, red) * (1.f/OUT);
  float lv=0;
#pragma unroll
  for (int p=0;p<H;p++){ float d=vals[p]-mu; lv += d*d; }
  float var = bsum256(lv, red) * (1.f/OUT);
  float inv = rsqrtf(var + 1e-5f);

  if constexpr (H==4){
    float4 g4 = *(const float4*)(ln_g + c0);
    float4 b4 = *(const float4*)(ln_b + c0);
    float o0 = fmaxf((vals[0]-mu)*inv*g4.x + b4.x, 0.f);
    float o1 = fmaxf((vals[1]-mu)*inv*g4.y + b4.y, 0.f);
    float o2 = fmaxf((vals[2]-mu)*inv*g4.z + b4.z, 0.f);
    float o3 = fmaxf((vals[3]-mu)*inv*g4.w + b4.w, 0.f);
    if (outb){
      ushort4 o;
      o.x=f2hu(o0); o.y=f2hu(o1); o.z=f2hu(o2); o.w=f2hu(o3);
      *(ushort4*)(outb + (size_t)i*OUT + c0) = o;
    } else {
      *(float4*)(outf + (size_t)i*OUT + c0) = make_float4(o0,o1,o2,o3);
    }
  } else {
    float y = fmaxf((vals[0]-mu)*inv*ln_g[c0] + ln_b[c0], 0.f);
    if (outb) outb[(size_t)i*OUT + c0] = f2hu(y);
    else      outf[(size_t)i*OUT + c0] = y;
  }
}

// ---------------- mean pool + classifier ----------------
__global__ void colsum_kernel(const float* __restrict__ h2, float* __restrict__ gsum, int n){
  int c = threadIdx.x; // 256
  float acc=0;
  for (int i=blockIdx.x;i<n;i+=gridDim.x) acc += h2[(size_t)i*256 + c];
  atomicAdd(&gsum[c], acc);
}

__launch_bounds__(128)
__global__ void cls_kernel(const float* __restrict__ gsum,
                           const float* __restrict__ w1, const float* __restrict__ b1,
                           const float* __restrict__ w2, const float* __restrict__ b2,
                           float* __restrict__ outp){
  __shared__ float g[256];
  __shared__ float hid[128];
  int t = threadIdx.x;
  g[t]     = gsum[t]    *(1.f/N_NODES);
  g[t+128] = gsum[t+128]*(1.f/N_NODES);
  __syncthreads();
  float a = b1[t];
  for (int c=0;c<256;c++) a = fmaf(g[c], w1[c*128+t], a);
  hid[t] = fmaxf(a, 0.f);
  __syncthreads();
  if (t<2){
    float o = b2[t];
    for (int j=0;j<128;j++) o = fmaf(hid[j], w2[j*2+t], o);
    outp[t] = o;
  }
}

// ---------------- launch ----------------
extern "C" void kernel_launch(void* const* d_in, const int* in_sizes, int n_in,
                              void* d_out, int out_size, void* d_ws, size_t ws_size,
                              hipStream_t stream)
{
  const float* x      = (const float*)d_in[0];
  const int*   ei     = (const int*)  d_in[1];
  const float* ea     = (const float*)d_in[2];
  const float* ca_qw  = (const float*)d_in[3];
  const float* ca_kw  = (const float*)d_in[5];
  const float* ca_kb  = (const float*)d_in[6];
  const float* ca_vw  = (const float*)d_in[7];
  const float* ca_vb  = (const float*)d_in[8];
  const float* ca_ow  = (const float*)d_in[9];
  const float* ca_ob  = (const float*)d_in[10];
  const float* g0_w   = (const float*)d_in[11];
  const float* g0_ew  = (const float*)d_in[12];
  const float* g0_as  = (const float*)d_in[13];
  const float* g0_ad  = (const float*)d_in[14];
  const float* g0_ae  = (const float*)d_in[15];
  const float* g0_b   = (const float*)d_in[16];
  const float* ln0_g  = (const float*)d_in[17];
  const float* ln0_b  = (const float*)d_in[18];
  const float* g1_w   = (const float*)d_in[19];
  const float* g1_ew  = (const float*)d_in[20];
  const float* g1_as  = (const float*)d_in[21];
  const float* g1_ad  = (const float*)d_in[22];
  const float* g1_ae  = (const float*)d_in[23];
  const float* g1_b   = (const float*)d_in[24];
  const float* ln1_g  = (const float*)d_in[25];
  const float* ln1_b  = (const float*)d_in[26];
  const float* g2_w   = (const float*)d_in[27];
  const float* g2_ew  = (const float*)d_in[28];
  const float* g2_as  = (const float*)d_in[29];
  const float* g2_ad  = (const float*)d_in[30];
  const float* g2_ae  = (const float*)d_in[31];
  const float* g2_b   = (const float*)d_in[32];
  const float* ln2_g  = (const float*)d_in[33];
  const float* ln2_b  = (const float*)d_in[34];
  const float* cls_w1 = (const float*)d_in[35];
  const float* cls_b1 = (const float*)d_in[36];
  const float* cls_w2 = (const float*)d_in[37];
  const float* cls_b2 = (const float*)d_in[38];
  float* outp = (float*)d_out;

  const int N = N_NODES, E = N_EDGES;

  char* base = (char*)d_ws;
  size_t o = 0;
  auto alloc = [&](size_t bytes)->void*{
    void* p = base + o;
    o += (bytes + 255) & ~(size_t)255;
    return p;
  };
  unsigned short* hF   = (unsigned short*)alloc((size_t)N*1024*2); // GEMM output h (f16)
  unsigned short* Af   = (unsigned short*)alloc((size_t)N*1280*2); // f16 activations (x, then agg out)
  float*          h2   = (float*)         alloc((size_t)N*256*4);  // layer-2 agg out (f32)
  unsigned short* Wt   = (unsigned short*)alloc((size_t)1280*1024*2);
  float* als       = (float*)alloc((size_t)N*4*4);
  float* ald       = (float*)alloc((size_t)N*4*4);
  float* scores    = (float*)alloc((size_t)N*4);
  float* wts       = (float*)alloc((size_t)N*4);
  int*   cnt       = (int*)  alloc((size_t)N*4);
  float* easum     = (float*)alloc((size_t)N*4);
  int*   off       = (int*)  alloc((size_t)(N+1)*4);
  int*   fill      = (int*)  alloc((size_t)N*4);
  int*   csr_src   = (int*)  alloc((size_t)E*4);
  float* csr_ea    = (float*)alloc((size_t)E*4);
  float* loop_attr = (float*)alloc((size_t)N*4);
  float* Kv        = (float*)alloc(256*4);
  float* Vv        = (float*)alloc(256*4);
  float* qK        = (float*)alloc(1280*4);
  float* Vo        = (float*)alloc(1280*4);
  float* obW       = (float*)alloc(1024*4);
  float* VoW       = (float*)alloc(1024*4);
  float* web       = (float*)alloc(16*4);
  float* gsum      = (float*)alloc(256*4);

  hipMemsetAsync(cnt,   0, (size_t)N*4, stream);
  hipMemsetAsync(easum, 0, (size_t)N*4, stream);
  hipMemsetAsync(fill,  0, (size_t)N*4, stream);
  hipMemsetAsync(gsum,  0, 256*4,       stream);

  // ---- edge preprocessing (CSR by dst) ----
  int eblocks = (E + 255)/256;
  edge_count_kernel<<<eblocks,256,0,stream>>>(ei, ea, cnt, easum, E);
  scan_kernel<<<1,1024,0,stream>>>(cnt, easum, off, loop_attr, N);
  edge_fill_kernel<<<eblocks,256,0,stream>>>(ei, ea, off, fill, csr_src, csr_ea, E);

  // ---- activations to f16 ----
  x_to_f16<<<2048,256,0,stream>>>(x, Af);

  // ---- cross-attention, rank-1 collapsed ----
  kv_kernel<<<1,256,0,stream>>>(x, ca_kw, ca_kb, ca_vw, ca_vb, Kv, Vv);
  qkvo_kernel<<<10,256,0,stream>>>(ca_qw, ca_ow, Kv, Vv, qK, Vo);
  obw_kernel<<<4,256,0,stream>>>(ca_ob, Vo, g0_w, obW, VoW);
  scores_kernel<<<(N+3)/4,256,0,stream>>>(x, qK, scores, N);
  softmax_nodes<<<1,1024,0,stream>>>(scores, wts, N);

  const int MB = (N + 127)/128; // 157

  // ---- layer 0 ----
  wt_f16_kernel<<<dim3(1280/32, 1024/32),256,0,stream>>>(g0_w, 1280, 1024, Wt);
  gemm_f16<<<dim3(1024/128, MB),256,0,stream>>>(Af, Wt, hF, N, 1024, 1280, obW, VoW, wts);
  alsd_kernel<4><<<N,256,0,stream>>>(hF, g0_as, g0_ad, als, ald, N);
  we_kernel<4><<<1,256,0,stream>>>(g0_ew, g0_ae, web);
  gat_agg_ln<4><<<N,256,0,stream>>>(hF, als, ald, off, csr_src, csr_ea, loop_attr,
                                    web, g0_b, ln0_g, ln0_b, nullptr, Af);

  // ---- layer 1 ----
  wt_f16_kernel<<<dim3(1024/32, 1024/32),256,0,stream>>>(g1_w, 1024, 1024, Wt);
  gemm_f16<<<dim3(1024/128, MB),256,0,stream>>>(Af, Wt, hF, N, 1024, 1024, nullptr, nullptr, nullptr);
  alsd_kernel<4><<<N,256,0,stream>>>(hF, g1_as, g1_ad, als, ald, N);
  we_kernel<4><<<1,256,0,stream>>>(g1_ew, g1_ae, web);
  gat_agg_ln<4><<<N,256,0,stream>>>(hF, als, ald, off, csr_src, csr_ea, loop_attr,
                                    web, g1_b, ln1_g, ln1_b, nullptr, Af);

  // ---- layer 2 (1 head, 256 out) ----
  wt_f16_kernel<<<dim3(1024/32, 256/32),256,0,stream>>>(g2_w, 1024, 256, Wt);
  gemm_f16<<<dim3(256/128, MB),256,0,stream>>>(Af, Wt, hF, N, 256, 1024, nullptr, nullptr, nullptr);
  alsd_kernel<1><<<(N+3)/4,256,0,stream>>>(hF, g2_as, g2_ad, als, ald, N);
  we_kernel<1><<<1,256,0,stream>>>(g2_ew, g2_ae, web);
  gat_agg_ln<1><<<N,256,0,stream>>>(hF, als, ald, off, csr_src, csr_ea, loop_attr,
                                    web, g2_b, ln2_g, ln2_b, h2, nullptr);

  // ---- mean pool + classifier ----
  colsum_kernel<<<256,256,0,stream>>>(h2, gsum, N);
  cls_kernel<<<1,128,0,stream>>>(gsum, cls_w1, cls_b1, cls_w2, cls_b2, outp);

  (void)in_sizes; (void)n_in; (void)out_size; (void)ws_size;
}

// Round 5
// 953.840 us; speedup vs baseline: 2.4964x; 1.1464x over previous
//
#include <hip/hip_runtime.h>
#include <hip/hip_bf16.h>
#include <math.h>

#define N_NODES 20000
#define N_EDGES 200000
#define XROW    1480   // EMB + MD

typedef __attribute__((ext_vector_type(8))) _Float16 f16x8;
typedef __attribute__((ext_vector_type(8))) unsigned short u16x8;
typedef __attribute__((ext_vector_type(4))) float f32x4v;

// ---------------- reduction helpers ----------------
__device__ __forceinline__ float wsum(float v){
#pragma unroll
  for (int o=32;o>0;o>>=1) v += __shfl_down(v,o);
  return v;
}
__device__ __forceinline__ float wmax(float v){
#pragma unroll
  for (int o=32;o>0;o>>=1) v = fmaxf(v,__shfl_down(v,o));
  return v;
}
// butterfly: result in ALL lanes
__device__ __forceinline__ float wsum_all(float v){
#pragma unroll
  for (int o=32;o>0;o>>=1) v += __shfl_xor(v,o);
  return v;
}
__device__ __forceinline__ float wmax_all(float v){
#pragma unroll
  for (int o=32;o>0;o>>=1) v = fmaxf(v,__shfl_xor(v,o));
  return v;
}

__device__ __forceinline__ unsigned short f2hu(float f){
  _Float16 h = (_Float16)f;
  return __builtin_bit_cast(unsigned short, h);
}
__device__ __forceinline__ float hu2f(unsigned short u){
  return (float)__builtin_bit_cast(_Float16, u);
}

__device__ __forceinline__ void async_copy16(void* lds, const void* g){
  __builtin_amdgcn_global_load_lds((const __attribute__((address_space(1))) void*)g,
                                   (__attribute__((address_space(3))) void*)lds, 16, 0, 0);
}

// ---------------- edge preprocessing (once, reused 3 layers) ----------------
__global__ void edge_count_kernel(const int* __restrict__ ei, const float* __restrict__ ea,
                                  int* __restrict__ cnt, float* __restrict__ easum, int E){
  int e = blockIdx.x*256 + threadIdx.x;
  if (e >= E) return;
  int dst = ei[E + e];
  atomicAdd(&cnt[dst], 1);
  atomicAdd(&easum[dst], ea[e]);
}

__launch_bounds__(1024)
__global__ void scan_kernel(const int* __restrict__ cnt, const float* __restrict__ easum,
                            int* __restrict__ off, float* __restrict__ loop_attr, int n){
  __shared__ int buf[1024];
  __shared__ int carry_s;
  if (threadIdx.x==0) carry_s = 0;
  __syncthreads();
  for (int base=0; base<n; base+=1024){
    int i = base + threadIdx.x;
    int v = (i<n)? cnt[i] : 0;
    if (i<n){
      loop_attr[i] = (v>0) ? easum[i]/(float)v : 0.f;  // fill='mean'
    }
    buf[threadIdx.x] = v;
    __syncthreads();
    for (int d2=1; d2<1024; d2<<=1){
      int tv = (threadIdx.x>=d2)? buf[threadIdx.x-d2] : 0;
      __syncthreads();
      buf[threadIdx.x] += tv;
      __syncthreads();
    }
    if (i<n) off[i] = carry_s + buf[threadIdx.x] - v;   // exclusive
    int tot = buf[1023];
    __syncthreads();
    if (threadIdx.x==0) carry_s += tot;
    __syncthreads();
  }
  if (threadIdx.x==0) off[n] = carry_s;
}

__global__ void edge_fill_kernel(const int* __restrict__ ei, const float* __restrict__ ea,
                                 const int* __restrict__ off, int* __restrict__ fill,
                                 int* __restrict__ csr_src, float* __restrict__ csr_ea, int E){
  int e = blockIdx.x*256 + threadIdx.x;
  if (e >= E) return;
  int dst = ei[E + e];
  int pos = off[dst] + atomicAdd(&fill[dst], 1);
  csr_src[pos] = ei[e];
  csr_ea[pos]  = ea[e];
}

// ---------------- conversions ----------------
// x[:, :1280] f32 -> f16 (row-major, stride 1280)
__global__ void x_to_f16(const float* __restrict__ x, unsigned short* __restrict__ xh){
  const int CH4 = 1280/4; // 320 float4 per row
  long total = (long)N_NODES*CH4;
  for (long i = (long)blockIdx.x*256 + threadIdx.x; i < total; i += (long)gridDim.x*256){
    int row = (int)(i / CH4), c4 = (int)(i % CH4);
    float4 v = *(const float4*)(x + (size_t)row*XROW + c4*4);
    ushort4 o;
    o.x = f2hu(v.x); o.y = f2hu(v.y); o.z = f2hu(v.z); o.w = f2hu(v.w);
    *(ushort4*)(xh + (size_t)row*1280 + c4*4) = o;
  }
}

// transpose: W[K,N] f32 -> Wt[N,K] f16
__global__ void wt_f16_kernel(const float* __restrict__ W, int K, int N,
                              unsigned short* __restrict__ Wt){
  __shared__ float tile[32][33];
  int k0 = blockIdx.x*32, n0 = blockIdx.y*32;
  int tx = threadIdx.x & 31, ty = threadIdx.x >> 5; // 32 x 8
  for (int r=ty; r<32; r+=8) tile[r][tx] = W[(size_t)(k0+r)*N + n0+tx];
  __syncthreads();
  for (int r=ty; r<32; r+=8){
    float w = tile[tx][r];               // = W[k0+tx][n0+r]
    Wt[(size_t)(n0+r)*K + k0+tx] = f2hu(w);
  }
}

// ---------------- cross-attention (rank-1 collapsed) ----------------
__global__ void kv_kernel(const float* __restrict__ x,
                          const float* __restrict__ kw, const float* __restrict__ kb,
                          const float* __restrict__ vw, const float* __restrict__ vb,
                          float* __restrict__ Kv, float* __restrict__ Vv){
  int j = threadIdx.x; // 256
  float ka = kb[j], va = vb[j];
  for (int k=0;k<200;k++){
    float m = x[1280+k];
    ka = fmaf(m, kw[k*256+j], ka);
    va = fmaf(m, vw[k*256+j], va);
  }
  Kv[j]=ka; Vv[j]=va;
}

__global__ void qkvo_kernel(const float* __restrict__ qw, const float* __restrict__ ow,
                            const float* __restrict__ Kv, const float* __restrict__ Vv,
                            float* __restrict__ qK, float* __restrict__ Vo){
  int idx = blockIdx.x*256 + threadIdx.x;
  if (idx < 1280){
    float a=0;
    for (int j=0;j<256;j++) a = fmaf(qw[idx*256+j], Kv[j], a);
    qK[idx]=a;
  } else if (idx < 2560){
    int j = idx-1280;
    float a=0;
    for (int i=0;i<256;i++) a = fmaf(Vv[i], ow[(size_t)i*1280+j], a);
    Vo[j]=a;
  }
}

__global__ void obw_kernel(const float* __restrict__ ob, const float* __restrict__ Vo,
                           const float* __restrict__ W, float* __restrict__ obW, float* __restrict__ VoW){
  int j = blockIdx.x*256 + threadIdx.x; // < 1024
  float a=0,b=0;
  for (int i=0;i<1280;i++){
    float w = W[(size_t)i*1024+j];
    a = fmaf(ob[i], w, a);
    b = fmaf(Vo[i], w, b);
  }
  obW[j]=a; VoW[j]=b;
}

__launch_bounds__(256)
__global__ void scores_kernel(const float* __restrict__ x, const float* __restrict__ qK,
                              float* __restrict__ scores, int n){
  __shared__ float qs[1280];
  int t = threadIdx.x;
  for (int i=t;i<1280;i+=256) qs[i]=qK[i];
  __syncthreads();
  int wid = t>>6, lane = t&63;
  int node = blockIdx.x*4 + wid;
  if (node >= n) return;
  const float4* row = (const float4*)(x + (size_t)node*XROW);
  float acc = 0;
#pragma unroll
  for (int it=0; it<5; it++){
    float4 v = row[lane + 64*it];
    float4 q = *(const float4*)&qs[4*(lane+64*it)];
    acc += v.x*q.x + v.y*q.y + v.z*q.z + v.w*q.w;
  }
  acc = wsum(acc);
  if (lane==0) scores[node] = acc;
}

__launch_bounds__(1024)
__global__ void softmax_nodes(const float* __restrict__ scores, float* __restrict__ wts, int n){
  __shared__ float red[16];
  int t = threadIdx.x, lane=t&63, wid=t>>6;
  float m = -INFINITY;
  for (int i=t;i<n;i+=1024) m = fmaxf(m, scores[i]);
  m = wmax(m);
  if (lane==0) red[wid]=m;
  __syncthreads();
  if (t==0){ float r=red[0]; for (int k=1;k<16;k++) r=fmaxf(r,red[k]); red[0]=r; }
  __syncthreads();
  float M = red[0];
  __syncthreads();
  float z=0;
  for (int i=t;i<n;i+=1024) z += expf((scores[i]-M)*(1.f/16.f));
  z = wsum(z);
  if (lane==0) red[wid]=z;
  __syncthreads();
  if (t==0){ float r=0; for (int k=0;k<16;k++) r+=red[k]; red[0]=r; }
  __syncthreads();
  float invZ = 1.f/red[0];
  for (int i=t;i<n;i+=1024) wts[i] = expf((scores[i]-M)*(1.f/16.f))*invZ;
}

// ---------------- f16 MFMA GEMM (TN): C[M,N] = A[M,K] @ B[N,K]^T ----------------
// 128x128 tile, BK=64, 256 threads (4 waves, 2x2 of 64x64), 16x16x32 f16 MFMA.
// Output f16. Grid: (N-tiles, M-tiles) so same-A blocks dispatch together.
__launch_bounds__(256)
__global__ void gemm_f16(const unsigned short* __restrict__ A,
                         const unsigned short* __restrict__ B,
                         unsigned short* __restrict__ C, int M, int N, int K,
                         const float* __restrict__ addCol,   // obW or null
                         const float* __restrict__ vCol,     // VoW
                         const float* __restrict__ wRow)     // wts
{
  __shared__ short lds[2*128*64];
  short* As = lds;
  short* Bs = lds + 128*64;

  const int t = threadIdx.x;
  const int w = t>>6, l = t&63;
  const int bn = blockIdx.x*128, bm = blockIdx.y*128;
  const int wr = (w>>1)*64, wc = (w&1)*64;

  f32x4v acc[4][4];
#pragma unroll
  for (int i=0;i<4;i++)
#pragma unroll
    for (int j=0;j<4;j++) acc[i][j] = (f32x4v){0.f,0.f,0.f,0.f};

  const unsigned short* Ap[4]; const unsigned short* Bp[4];
  int ldsOff[4];
#pragma unroll
  for (int q=0;q<4;q++){
    int p  = (w*4+q)*64 + l;       // phys 16B-chunk
    int r  = p>>3, pc = p&7;
    int kc = (pc ^ (r&7))*8;       // logical k element offset (XOR swizzle)
    int rowA = bm + r; if (rowA > M-1) rowA = M-1;
    Ap[q] = A + (size_t)rowA*K + kc;
    Bp[q] = B + (size_t)(bn+r)*K + kc;
    ldsOff[q] = (w*4+q)*64*8;      // shorts (wave-uniform base; lane spreads x16B)
  }

  for (int k0=0; k0<K; k0+=64){
#pragma unroll
    for (int q=0;q<4;q++) async_copy16(As + ldsOff[q], Ap[q] + k0);
#pragma unroll
    for (int q=0;q<4;q++) async_copy16(Bs + ldsOff[q], Bp[q] + k0);
    __syncthreads();

    const int q4 = l>>4, m16 = l&15;
#pragma unroll
    for (int ks=0; ks<2; ks++){
      f16x8 af[4], bf[4];
      const int c = ks*4 + q4;
#pragma unroll
      for (int i=0;i<4;i++){
        int ra = wr + i*16 + m16;
        af[i] = *(const f16x8*)&As[ra*64 + ((c ^ (ra&7))*8)];
        int rb = wc + i*16 + m16;
        bf[i] = *(const f16x8*)&Bs[rb*64 + ((c ^ (rb&7))*8)];
      }
#pragma unroll
      for (int i=0;i<4;i++)
#pragma unroll
        for (int j=0;j<4;j++)
          acc[i][j] = __builtin_amdgcn_mfma_f32_16x16x32_f16(af[i], bf[j], acc[i][j], 0,0,0);
    }
    __syncthreads();
  }

  // epilogue: C/D layout col = l&15, row = (l>>4)*4 + r ; f32 math then f16 store
  const int q4 = l>>4, m16 = l&15;
#pragma unroll
  for (int i=0;i<4;i++){
#pragma unroll
    for (int r=0;r<4;r++){
      int m = bm + wr + i*16 + q4*4 + r;
      if (m >= M) continue;
      float wrow = addCol ? wRow[m] : 0.f;
      unsigned short* crow = C + (size_t)m*N;
#pragma unroll
      for (int j=0;j<4;j++){
        int n = bn + wc + j*16 + m16;
        float v = acc[i][j][r];
        if (addCol) v += addCol[n] + wrow*vCol[n];
        crow[n] = f2hu(v);
      }
    }
  }
}

// ---------------- attention logits per node/head (f16 h) ----------------
template<int H>
__launch_bounds__(256)
__global__ void alsd_kernel(const unsigned short* __restrict__ h,
                            const float* __restrict__ a_src, const float* __restrict__ a_dst,
                            float* __restrict__ als, float* __restrict__ ald, int n){
  int gw = (blockIdx.x*256 + threadIdx.x) >> 6;
  int lane = threadIdx.x & 63;
  if (gw >= n*H) return;
  int node = gw / H, hd = gw % H;
  const ushort4* row = (const ushort4*)(h + (size_t)node*(256*H) + hd*256);
  const float4* as  = (const float4*)(a_src + hd*256);
  const float4* ad  = (const float4*)(a_dst + hd*256);
  ushort4 ru = row[lane];
  float4 a = as[lane], b = ad[lane];
  float rx=hu2f(ru.x), ry=hu2f(ru.y), rz=hu2f(ru.z), rw=hu2f(ru.w);
  float s = rx*a.x + ry*a.y + rz*a.z + rw*a.w;
  float d = rx*b.x + ry*b.y + rz*b.z + rw*b.w;
  s = wsum(s); d = wsum(d);
  if (lane==0){ als[(size_t)node*H+hd]=s; ald[(size_t)node*H+hd]=d; }
}

template<int H>
__global__ void we_kernel(const float* __restrict__ We, const float* __restrict__ a_edge,
                          float* __restrict__ we){
  int wid = threadIdx.x>>6, lane = threadIdx.x&63;
  if (wid < H){
    const float4* w4 = (const float4*)(We + wid*256);
    const float4* a4 = (const float4*)(a_edge + wid*256);
    float4 a = w4[lane], b = a4[lane];
    float v = a.x*b.x + a.y*b.y + a.z*b.z + a.w*b.w;
    v = wsum(v);
    if (lane==0) we[wid]=v;
  }
}

// ---------------- fused alpha-softmax + aggregate + bias + LN + ReLU ----------------
// ONE WAVE PER NODE (4 waves/block, no __syncthreads). h is f16.
// outb != null -> write f16 (feeds next GEMM); else f32 to outf.
template<int H>
__launch_bounds__(256)
__global__ void gat_agg_ln_wave(const unsigned short* __restrict__ hmat,
                           const float* __restrict__ als, const float* __restrict__ ald,
                           const int* __restrict__ off, const int* __restrict__ csr_src,
                           const float* __restrict__ csr_ea, const float* __restrict__ loop_attr,
                           const float* __restrict__ we,
                           const float* __restrict__ bias,
                           const float* __restrict__ ln_g, const float* __restrict__ ln_b,
                           float* __restrict__ outf, unsigned short* __restrict__ outb, int n)
{
  constexpr int OUT = 256*H;      // 1024 or 256
  constexpr int CPL = OUT/64;     // channels per lane: 16 or 4
  const int wv = threadIdx.x>>6, lane = threadIdx.x&63;
  const int i = blockIdx.x*4 + wv;
  __shared__ float wbuf_s[4][64*H];
  __shared__ int   sbuf_s[4][64];
  if (i >= n) return;
  float* wbuf = wbuf_s[wv];
  int*   sbuf = sbuf_s[wv];

  const int begin = off[i];
  const int deg   = off[i+1]-begin;
  const int S     = deg + 1;           // + self-loop

  float aldi[H], wei[H];
#pragma unroll
  for (int hh=0;hh<H;hh++){ aldi[hh]=ald[(size_t)i*H+hh]; wei[hh]=we[hh]; }
  const float lea = loop_attr[i];

  const int head = (lane*CPL) >> 8;    // which head this lane's channels belong to
  const int c0   = lane*CPL;
  float acc[CPL];
#pragma unroll
  for (int c=0;c<CPL;c++) acc[c]=0.f;

  if (S <= 64){
    // ---- fast path: lane == edge slot; alphas live in registers ----
    int src = i; float ev = lea;
    if (lane < deg){ src = csr_src[begin+lane]; ev = csr_ea[begin+lane]; }
    const bool act = lane < S;
    float a[H];
#pragma unroll
    for (int hh=0;hh<H;hh++){
      float v = als[(size_t)src*H+hh] + aldi[hh] + ev*wei[hh];
      a[hh] = v>0.f ? v : 0.2f*v;
    }
#pragma unroll
    for (int hh=0;hh<H;hh++){
      float M = wmax_all(act ? a[hh] : -INFINITY);
      float e = act ? __expf(a[hh]-M) : 0.f;
      float Z = wsum_all(e);
      wbuf[lane*H+hh] = e / (Z + 1e-16f);
    }
    sbuf[lane] = src;
    for (int j=0;j<S;j++){
      int sj = sbuf[j];
      float wj = wbuf[j*H+head];
      const unsigned short* row = hmat + (size_t)sj*OUT + c0;
      if constexpr (CPL==16){
        u16x8 r0 = *(const u16x8*)(row);
        u16x8 r1 = *(const u16x8*)(row+8);
#pragma unroll
        for (int c=0;c<8;c++){
          acc[c]   = fmaf(wj, hu2f(r0[c]), acc[c]);
          acc[8+c] = fmaf(wj, hu2f(r1[c]), acc[8+c]);
        }
      } else {
        ushort4 r = *(const ushort4*)(row);
        acc[0]=fmaf(wj,hu2f(r.x),acc[0]); acc[1]=fmaf(wj,hu2f(r.y),acc[1]);
        acc[2]=fmaf(wj,hu2f(r.z),acc[2]); acc[3]=fmaf(wj,hu2f(r.w),acc[3]);
      }
    }
  } else {
    // ---- slow path (deg >= 64, vanishingly rare): chunked recompute ----
    float rm[H];
#pragma unroll
    for (int hh=0;hh<H;hh++) rm[hh] = -INFINITY;
    for (int s=lane; s<S; s+=64){
      int src = (s<deg)? csr_src[begin+s] : i;
      float ev = (s<deg)? csr_ea[begin+s] : lea;
#pragma unroll
      for (int hh=0;hh<H;hh++){
        float v = als[(size_t)src*H+hh] + aldi[hh] + ev*wei[hh];
        v = v>0.f? v : 0.2f*v;
        rm[hh] = fmaxf(rm[hh], v);
      }
    }
    float M[H], es[H];
#pragma unroll
    for (int hh=0;hh<H;hh++){ M[hh]=wmax_all(rm[hh]); es[hh]=0.f; }
    for (int s=lane; s<S; s+=64){
      int src = (s<deg)? csr_src[begin+s] : i;
      float ev = (s<deg)? csr_ea[begin+s] : lea;
#pragma unroll
      for (int hh=0;hh<H;hh++){
        float v = als[(size_t)src*H+hh] + aldi[hh] + ev*wei[hh];
        v = v>0.f? v : 0.2f*v;
        es[hh] += __expf(v - M[hh]);
      }
    }
    float invZ[H];
#pragma unroll
    for (int hh=0;hh<H;hh++) invZ[hh] = 1.f/(wsum_all(es[hh]) + 1e-16f);
    for (int cb=0; cb<S; cb+=64){
      int m = min(64, S-cb);
      int s = cb + lane;
      if (s < S){
        int src = (s<deg)? csr_src[begin+s] : i;
        float ev = (s<deg)? csr_ea[begin+s] : lea;
        sbuf[lane] = src;
#pragma unroll
        for (int hh=0;hh<H;hh++){
          float v = als[(size_t)src*H+hh] + aldi[hh] + ev*wei[hh];
          v = v>0.f? v : 0.2f*v;
          wbuf[lane*H+hh] = __expf(v - M[hh]) * invZ[hh];
        }
      }
      for (int j=0;j<m;j++){
        int sj = sbuf[j];
        float wj = wbuf[j*H+head];
        const unsigned short* row = hmat + (size_t)sj*OUT + c0;
        if constexpr (CPL==16){
          u16x8 r0 = *(const u16x8*)(row);
          u16x8 r1 = *(const u16x8*)(row+8);
#pragma unroll
          for (int c=0;c<8;c++){
            acc[c]   = fmaf(wj, hu2f(r0[c]), acc[c]);
            acc[8+c] = fmaf(wj, hu2f(r1[c]), acc[8+c]);
          }
        } else {
          ushort4 r = *(const ushort4*)(row);
          acc[0]=fmaf(wj,hu2f(r.x),acc[0]); acc[1]=fmaf(wj,hu2f(r.y),acc[1]);
          acc[2]=fmaf(wj,hu2f(r.z),acc[2]); acc[3]=fmaf(wj,hu2f(r.w),acc[3]);
        }
      }
    }
  }

  // ---- bias + LayerNorm + ReLU (wave-level) ----
  float vals[CPL];
  float ls=0.f;
#pragma unroll
  for (int c=0;c<CPL;c+=4){
    float4 b4 = *(const float4*)(bias + c0 + c);
    vals[c]=acc[c]+b4.x; vals[c+1]=acc[c+1]+b4.y; vals[c+2]=acc[c+2]+b4.z; vals[c+3]=acc[c+3]+b4.w;
    ls += vals[c]+vals[c+1]+vals[c+2]+vals[c+3];
  }
  float mu = wsum_all(ls) * (1.f/OUT);
  float lv=0.f;
#pragma unroll
  for (int c=0;c<CPL;c++){ float d=vals[c]-mu; lv += d*d; }
  float inv = rsqrtf(wsum_all(lv)*(1.f/OUT) + 1e-5f);

  if (outb){
#pragma unroll
    for (int c=0;c<CPL;c+=8){
      u16x8 o;
#pragma unroll
      for (int k=0;k<8;k++){
        float g = ln_g[c0+c+k], b = ln_b[c0+c+k];
        o[k] = f2hu(fmaxf((vals[c+k]-mu)*inv*g + b, 0.f));
      }
      *(u16x8*)(outb + (size_t)i*OUT + c0 + c) = o;
    }
    if constexpr (CPL==4){
      // CPL==4 can't use the 8-wide store loop above; handled below
    }
  }
  if (outb && CPL==4){
    ushort4 o;
    o.x = f2hu(fmaxf((vals[0]-mu)*inv*ln_g[c0+0] + ln_b[c0+0], 0.f));
    o.y = f2hu(fmaxf((vals[1]-mu)*inv*ln_g[c0+1] + ln_b[c0+1], 0.f));
    o.z = f2hu(fmaxf((vals[2]-mu)*inv*ln_g[c0+2] + ln_b[c0+2], 0.f));
    o.w = f2hu(fmaxf((vals[3]-mu)*inv*ln_g[c0+3] + ln_b[c0+3], 0.f));
    *(ushort4*)(outb + (size_t)i*OUT + c0) = o;
  }
  if (!outb){
#pragma unroll
    for (int c=0;c<CPL;c+=4){
      float4 g4 = *(const float4*)(ln_g + c0 + c);
      float4 b4 = *(const float4*)(ln_b + c0 + c);
      float4 o;
      o.x = fmaxf((vals[c+0]-mu)*inv*g4.x + b4.x, 0.f);
      o.y = fmaxf((vals[c+1]-mu)*inv*g4.y + b4.y, 0.f);
      o.z = fmaxf((vals[c+2]-mu)*inv*g4.z + b4.z, 0.f);
      o.w = fmaxf((vals[c+3]-mu)*inv*g4.w + b4.w, 0.f);
      *(float4*)(outf + (size_t)i*OUT + c0 + c) = o;
    }
  }
}

// ---------------- mean pool + classifier ----------------
__global__ void colsum_kernel(const float* __restrict__ h2, float* __restrict__ gsum, int n){
  int c = threadIdx.x; // 256
  float acc=0;
  for (int i=blockIdx.x;i<n;i+=gridDim.x) acc += h2[(size_t)i*256 + c];
  atomicAdd(&gsum[c], acc);
}

__launch_bounds__(128)
__global__ void cls_kernel(const float* __restrict__ gsum,
                           const float* __restrict__ w1, const float* __restrict__ b1,
                           const float* __restrict__ w2, const float* __restrict__ b2,
                           float* __restrict__ outp){
  __shared__ float g[256];
  __shared__ float hid[128];
  int t = threadIdx.x;
  g[t]     = gsum[t]    *(1.f/N_NODES);
  g[t+128] = gsum[t+128]*(1.f/N_NODES);
  __syncthreads();
  float a = b1[t];
  for (int c=0;c<256;c++) a = fmaf(g[c], w1[c*128+t], a);
  hid[t] = fmaxf(a, 0.f);
  __syncthreads();
  if (t<2){
    float o = b2[t];
    for (int j=0;j<128;j++) o = fmaf(hid[j], w2[j*2+t], o);
    outp[t] = o;
  }
}

// ---------------- launch ----------------
extern "C" void kernel_launch(void* const* d_in, const int* in_sizes, int n_in,
                              void* d_out, int out_size, void* d_ws, size_t ws_size,
                              hipStream_t stream)
{
  const float* x      = (const float*)d_in[0];
  const int*   ei     = (const int*)  d_in[1];
  const float* ea     = (const float*)d_in[2];
  const float* ca_qw  = (const float*)d_in[3];
  const float* ca_kw  = (const float*)d_in[5];
  const float* ca_kb  = (const float*)d_in[6];
  const float* ca_vw  = (const float*)d_in[7];
  const float* ca_vb  = (const float*)d_in[8];
  const float* ca_ow  = (const float*)d_in[9];
  const float* ca_ob  = (const float*)d_in[10];
  const float* g0_w   = (const float*)d_in[11];
  const float* g0_ew  = (const float*)d_in[12];
  const float* g0_as  = (const float*)d_in[13];
  const float* g0_ad  = (const float*)d_in[14];
  const float* g0_ae  = (const float*)d_in[15];
  const float* g0_b   = (const float*)d_in[16];
  const float* ln0_g  = (const float*)d_in[17];
  const float* ln0_b  = (const float*)d_in[18];
  const float* g1_w   = (const float*)d_in[19];
  const float* g1_ew  = (const float*)d_in[20];
  const float* g1_as  = (const float*)d_in[21];
  const float* g1_ad  = (const float*)d_in[22];
  const float* g1_ae  = (const float*)d_in[23];
  const float* g1_b   = (const float*)d_in[24];
  const float* ln1_g  = (const float*)d_in[25];
  const float* ln1_b  = (const float*)d_in[26];
  const float* g2_w   = (const float*)d_in[27];
  const float* g2_ew  = (const float*)d_in[28];
  const float* g2_as  = (const float*)d_in[29];
  const float* g2_ad  = (const float*)d_in[30];
  const float* g2_ae  = (const float*)d_in[31];
  const float* g2_b   = (const float*)d_in[32];
  const float* ln2_g  = (const float*)d_in[33];
  const float* ln2_b  = (const float*)d_in[34];
  const float* cls_w1 = (const float*)d_in[35];
  const float* cls_b1 = (const float*)d_in[36];
  const float* cls_w2 = (const float*)d_in[37];
  const float* cls_b2 = (const float*)d_in[38];
  float* outp = (float*)d_out;

  const int N = N_NODES, E = N_EDGES;

  char* base = (char*)d_ws;
  size_t o = 0;
  auto alloc = [&](size_t bytes)->void*{
    void* p = base + o;
    o += (bytes + 255) & ~(size_t)255;
    return p;
  };
  unsigned short* hF   = (unsigned short*)alloc((size_t)N*1024*2); // GEMM output h (f16)
  unsigned short* Af   = (unsigned short*)alloc((size_t)N*1280*2); // f16 activations (x, then agg out)
  float*          h2   = (float*)         alloc((size_t)N*256*4);  // layer-2 agg out (f32)
  unsigned short* Wt   = (unsigned short*)alloc((size_t)1280*1024*2);
  float* als       = (float*)alloc((size_t)N*4*4);
  float* ald       = (float*)alloc((size_t)N*4*4);
  float* scores    = (float*)alloc((size_t)N*4);
  float* wts       = (float*)alloc((size_t)N*4);
  int*   cnt       = (int*)  alloc((size_t)N*4);
  float* easum     = (float*)alloc((size_t)N*4);
  int*   off       = (int*)  alloc((size_t)(N+1)*4);
  int*   fill      = (int*)  alloc((size_t)N*4);
  int*   csr_src   = (int*)  alloc((size_t)E*4);
  float* csr_ea    = (float*)alloc((size_t)E*4);
  float* loop_attr = (float*)alloc((size_t)N*4);
  float* Kv        = (float*)alloc(256*4);
  float* Vv        = (float*)alloc(256*4);
  float* qK        = (float*)alloc(1280*4);
  float* Vo        = (float*)alloc(1280*4);
  float* obW       = (float*)alloc(1024*4);
  float* VoW       = (float*)alloc(1024*4);
  float* web       = (float*)alloc(16*4);
  float* gsum      = (float*)alloc(256*4);

  hipMemsetAsync(cnt,   0, (size_t)N*4, stream);
  hipMemsetAsync(easum, 0, (size_t)N*4, stream);
  hipMemsetAsync(fill,  0, (size_t)N*4, stream);
  hipMemsetAsync(gsum,  0, 256*4,       stream);

  // ---- edge preprocessing (CSR by dst) ----
  int eblocks = (E + 255)/256;
  edge_count_kernel<<<eblocks,256,0,stream>>>(ei, ea, cnt, easum, E);
  scan_kernel<<<1,1024,0,stream>>>(cnt, easum, off, loop_attr, N);
  edge_fill_kernel<<<eblocks,256,0,stream>>>(ei, ea, off, fill, csr_src, csr_ea, E);

  // ---- activations to f16 ----
  x_to_f16<<<2048,256,0,stream>>>(x, Af);

  // ---- cross-attention, rank-1 collapsed ----
  kv_kernel<<<1,256,0,stream>>>(x, ca_kw, ca_kb, ca_vw, ca_vb, Kv, Vv);
  qkvo_kernel<<<10,256,0,stream>>>(ca_qw, ca_ow, Kv, Vv, qK, Vo);
  obw_kernel<<<4,256,0,stream>>>(ca_ob, Vo, g0_w, obW, VoW);
  scores_kernel<<<(N+3)/4,256,0,stream>>>(x, qK, scores, N);
  softmax_nodes<<<1,1024,0,stream>>>(scores, wts, N);

  const int MB = (N + 127)/128; // 157
  const int NB4 = (N + 3)/4;    // wave-per-node blocks

  // ---- layer 0 ----
  wt_f16_kernel<<<dim3(1280/32, 1024/32),256,0,stream>>>(g0_w, 1280, 1024, Wt);
  gemm_f16<<<dim3(1024/128, MB),256,0,stream>>>(Af, Wt, hF, N, 1024, 1280, obW, VoW, wts);
  alsd_kernel<4><<<N,256,0,stream>>>(hF, g0_as, g0_ad, als, ald, N);
  we_kernel<4><<<1,256,0,stream>>>(g0_ew, g0_ae, web);
  gat_agg_ln_wave<4><<<NB4,256,0,stream>>>(hF, als, ald, off, csr_src, csr_ea, loop_attr,
                                           web, g0_b, ln0_g, ln0_b, nullptr, Af, N);

  // ---- layer 1 ----
  wt_f16_kernel<<<dim3(1024/32, 1024/32),256,0,stream>>>(g1_w, 1024, 1024, Wt);
  gemm_f16<<<dim3(1024/128, MB),256,0,stream>>>(Af, Wt, hF, N, 1024, 1024, nullptr, nullptr, nullptr);
  alsd_kernel<4><<<N,256,0,stream>>>(hF, g1_as, g1_ad, als, ald, N);
  we_kernel<4><<<1,256,0,stream>>>(g1_ew, g1_ae, web);
  gat_agg_ln_wave<4><<<NB4,256,0,stream>>>(hF, als, ald, off, csr_src, csr_ea, loop_attr,
                                           web, g1_b, ln1_g, ln1_b, nullptr, Af, N);

  // ---- layer 2 (1 head, 256 out) ----
  wt_f16_kernel<<<dim3(1024/32, 256/32),256,0,stream>>>(g2_w, 1024, 256, Wt);
  gemm_f16<<<dim3(256/128, MB),256,0,stream>>>(Af, Wt, hF, N, 256, 1024, nullptr, nullptr, nullptr);
  alsd_kernel<1><<<(N+3)/4,256,0,stream>>>(hF, g2_as, g2_ad, als, ald, N);
  we_kernel<1><<<1,256,0,stream>>>(g2_ew, g2_ae, web);
  gat_agg_ln_wave<1><<<NB4,256,0,stream>>>(hF, als, ald, off, csr_src, csr_ea, loop_attr,
                                           web, g2_b, ln2_g, ln2_b, h2, nullptr, N);

  // ---- mean pool + classifier ----
  colsum_kernel<<<256,256,0,stream>>>(h2, gsum, N);
  cls_kernel<<<1,128,0,stream>>>(gsum, cls_w1, cls_b1, cls_w2, cls_b2, outp);

  (void)in_sizes; (void)n_in; (void)out_size; (void)ws_size;
}